// Round 2
// baseline (9804.562 us; speedup 1.0000x reference)
//
#include <hip/hip_runtime.h>

// EGNN layer: N=50000 nodes, E=800000 edges, H=256.
// bf16 MFMA for all GEMMs, f32 for LN/reductions/atomics.
// Feedback GEMM reduced E->N rows via linearity of segment_sum.
// Workspace-lean: persistent ~57MB + one adaptive arena reused across
// edge-chunk / node-chunk / feedback-chunk phases.

#define NN 50000
#define EE 800000

typedef unsigned short u16;
typedef float f32x4 __attribute__((ext_vector_type(4)));
typedef short bf16x8 __attribute__((ext_vector_type(8)));

__device__ __forceinline__ u16 f2bf(float f) {
  unsigned u = __float_as_uint(f);
  u = (u + 0x7FFFu + ((u >> 16) & 1u)) >> 16;
  return (u16)u;
}
__device__ __forceinline__ float bf2f(u16 s) {
  return __uint_as_float(((unsigned)s) << 16);
}
__device__ __forceinline__ float silu_f(float x) { return x / (1.f + __expf(-x)); }

// ---------------- generic MFMA GEMM: out = act(A[M,K] @ BT[N,K]^T + bias) ----
// MODE 0: silu -> bf16 out ; MODE 1: none -> f32 out ;
// MODE 2: f32 out += scale*(acc + cnt[m]*b2[n])
template <int MODE>
__global__ __launch_bounds__(256) void gemm_k(
    const u16* __restrict__ A, const u16* __restrict__ BT,
    const float* __restrict__ bias, void* __restrict__ outp,
    int M, int Nc, int K,
    const float* __restrict__ cnt, const float* __restrict__ b2, float scale) {
  __shared__ __align__(16) u16 As[64][32];
  __shared__ __align__(16) u16 Bs[64][32];
  const int tid = threadIdx.x;
  const int m0 = blockIdx.x * 64, n0 = blockIdx.y * 64;
  const int w = tid >> 6, lane = tid & 63;
  const int sr = tid >> 2, skc = (tid & 3) * 8;   // staging row / k-offset
  const int l15 = lane & 15, koff = (lane >> 4) * 8;

  f32x4 acc[4] = {};

  for (int k0 = 0; k0 < K; k0 += 32) {
    int ar = m0 + sr;
    uint4 av = make_uint4(0u, 0u, 0u, 0u);
    if (ar < M) av = *reinterpret_cast<const uint4*>(&A[(size_t)ar * K + k0 + skc]);
    *reinterpret_cast<uint4*>(&As[sr][skc]) = av;
    uint4 bv = *reinterpret_cast<const uint4*>(&BT[(size_t)(n0 + sr) * K + k0 + skc]);
    *reinterpret_cast<uint4*>(&Bs[sr][skc]) = bv;
    __syncthreads();
    bf16x8 a = *reinterpret_cast<const bf16x8*>(&As[16 * w + l15][koff]);
#pragma unroll
    for (int j = 0; j < 4; j++) {
      bf16x8 b = *reinterpret_cast<const bf16x8*>(&Bs[16 * j + l15][koff]);
      acc[j] = __builtin_amdgcn_mfma_f32_16x16x32_bf16(a, b, acc[j], 0, 0, 0);
    }
    __syncthreads();
  }

  const int rbase = m0 + 16 * w + ((lane >> 4) << 2);
#pragma unroll
  for (int j = 0; j < 4; j++) {
    int gc = n0 + 16 * j + l15;
    float bz = (MODE == 2) ? 0.f : bias[gc];
#pragma unroll
    for (int t = 0; t < 4; t++) {
      int gr = rbase + t;
      if (gr >= M) continue;
      size_t oi = (size_t)gr * Nc + gc;
      float v = acc[j][t] + bz;
      if (MODE == 0) {
        ((u16*)outp)[oi] = f2bf(silu_f(v));
      } else if (MODE == 1) {
        ((float*)outp)[oi] = v;
      } else {
        ((float*)outp)[oi] += scale * (v + cnt[gr] * b2[gc]);
      }
    }
  }
}

// ---------------- weight transpose + bf16 convert: src[K,N] -> dst[N,Kpad] ---
__global__ void wtrans(const float* __restrict__ src, u16* __restrict__ dst,
                       int K, int Nn, int Kpad) {
  int t = blockIdx.x * 256 + threadIdx.x;
  if (t >= Nn * Kpad) return;
  int n = t / Kpad, k = t - n * Kpad;
  float v = (k < K) ? src[(size_t)k * Nn + n] : 0.f;
  dst[t] = f2bf(v);
}

// ---------------- per-edge geometry + degree count ---------------------------
__global__ void edge_geom(const float* __restrict__ pos, const int* __restrict__ row,
                          const int* __restrict__ colx, float* __restrict__ dist,
                          float* __restrict__ cnt) {
  int e = blockIdx.x * 256 + threadIdx.x;
  if (e >= EE) return;
  int r = row[e], c = colx[e];
  float d0 = pos[r * 3 + 0] - pos[c * 3 + 0];
  float d1 = pos[r * 3 + 1] - pos[c * 3 + 1];
  float d2 = pos[r * 3 + 2] - pos[c * 3 + 2];
  float nr = sqrtf(d0 * d0 + d1 * d1 + d2 * d2);
  dist[e] = fmaxf(nr, 1e-5f);
  atomicAdd(&cnt[r], 1.f);
}

// ---------------- gather edge_in tile -> bf16 --------------------------------
__global__ void build_ain(const float* __restrict__ h, const int* __restrict__ row,
                          const int* __restrict__ colx, const float* __restrict__ dist,
                          const float* __restrict__ eattr, u16* __restrict__ Ain,
                          int e0, int ce) {
  int t = blockIdx.x * 256 + threadIdx.x;
  if (t >= ce * 544) return;
  int le = t / 544, k = t - le * 544;
  int e = e0 + le;
  float v = 0.f;
  if (k < 256) v = h[(size_t)row[e] * 256 + k];
  else if (k < 512) v = h[(size_t)colx[e] * 256 + (k - 256)];
  else if (k == 512) v = dist[e];
  else if (k < 526) v = eattr[(size_t)e * 13 + (k - 513)];
  Ain[t] = f2bf(v);
}

// ---------------- in-place row LayerNorm on bf16, D=512 ----------------------
__global__ __launch_bounds__(128) void ln_512(u16* __restrict__ t,
                                              const float* __restrict__ g,
                                              const float* __restrict__ b) {
  int row = blockIdx.x, tid = threadIdx.x;
  size_t base = (size_t)row * 512 + tid * 4;
  ushort4 xv = *reinterpret_cast<const ushort4*>(&t[base]);
  float x0 = bf2f(xv.x), x1 = bf2f(xv.y), x2 = bf2f(xv.z), x3 = bf2f(xv.w);
  float s1 = x0 + x1 + x2 + x3;
  float s2 = x0 * x0 + x1 * x1 + x2 * x2 + x3 * x3;
  for (int o = 32; o; o >>= 1) { s1 += __shfl_xor(s1, o); s2 += __shfl_xor(s2, o); }
  __shared__ float red[4];
  if ((tid & 63) == 0) { red[tid >> 6] = s1; red[2 + (tid >> 6)] = s2; }
  __syncthreads();
  s1 = red[0] + red[1]; s2 = red[2] + red[3];
  float mu = s1 * (1.f / 512.f);
  float var = s2 * (1.f / 512.f) - mu * mu;
  float inv = rsqrtf(var + 1e-5f);
  int c = tid * 4;
  ushort4 yv;
  yv.x = f2bf((x0 - mu) * inv * g[c + 0] + b[c + 0]);
  yv.y = f2bf((x1 - mu) * inv * g[c + 1] + b[c + 1]);
  yv.z = f2bf((x2 - mu) * inv * g[c + 2] + b[c + 2]);
  yv.w = f2bf((x3 - mu) * inv * g[c + 3] + b[c + 3]);
  *reinterpret_cast<ushort4*>(&t[base]) = yv;
}

// ---------------- per-edge attention + scatter (wave per edge) ---------------
__global__ __launch_bounds__(256) void edge_scatter(
    const u16* __restrict__ m, const u16* __restrict__ c1,
    const int* __restrict__ row, const int* __restrict__ colx,
    const float* __restrict__ pos,
    const float* __restrict__ Wa, const float* __restrict__ ba,
    const float* __restrict__ Wc2,
    float* __restrict__ agg, float* __restrict__ cagg, int e0, int ce) {
  int w = threadIdx.x >> 6, lane = threadIdx.x & 63;
  int le = blockIdx.x * 4 + w;
  if (le >= ce) return;
  int e = e0 + le;
  size_t mb = (size_t)le * 256 + lane * 4;
  float mv[4], sa = 0.f, sc = 0.f;
#pragma unroll
  for (int i = 0; i < 4; i++) {
    mv[i] = bf2f(m[mb + i]);
    sa += mv[i] * Wa[lane * 4 + i];
    sc += bf2f(c1[mb + i]) * Wc2[lane * 4 + i];
  }
  for (int o = 32; o; o >>= 1) { sa += __shfl_xor(sa, o); sc += __shfl_xor(sc, o); }
  float att = 1.f / (1.f + __expf(-(sa + ba[0])));
  int r = row[e];
  float* ag = agg + (size_t)r * 256 + lane * 4;
#pragma unroll
  for (int i = 0; i < 4; i++) atomicAdd(ag + i, att * mv[i]);
  if (lane < 3) {
    int c = colx[e];
    float d0 = pos[r * 3 + 0] - pos[c * 3 + 0];
    float d1 = pos[r * 3 + 1] - pos[c * 3 + 1];
    float d2 = pos[r * 3 + 2] - pos[c * 3 + 2];
    float dsel = (lane == 0) ? d0 : ((lane == 1) ? d1 : d2);
    atomicAdd(&cagg[r * 3 + lane], sc * dsel);
  }
}

// ---------------- node_in chunk = [h | agg] -> bf16 --------------------------
__global__ void build_nodein(const float* __restrict__ h, const float* __restrict__ agg,
                             u16* __restrict__ ni, int cn) {
  int t = blockIdx.x * 256 + threadIdx.x;
  if (t >= cn * 512) return;
  int n = t >> 9, k = t & 511;
  float v = (k < 256) ? h[(size_t)n * 256 + k] : agg[(size_t)n * 256 + (k - 256)];
  ni[t] = f2bf(v);
}

// ---------------- final h LN: out = LN(h + hupd)*g + b (f32) -----------------
__global__ __launch_bounds__(64) void hmid_ln(const float* __restrict__ h,
                                              const float* __restrict__ hupd,
                                              const float* __restrict__ g,
                                              const float* __restrict__ b,
                                              float* __restrict__ outp) {
  int row = blockIdx.x, lane = threadIdx.x;
  size_t base = (size_t)row * 256 + lane * 4;
  float x[4];
#pragma unroll
  for (int i = 0; i < 4; i++) x[i] = h[base + i] + hupd[base + i];
  float s1 = x[0] + x[1] + x[2] + x[3];
  float s2 = x[0] * x[0] + x[1] * x[1] + x[2] * x[2] + x[3] * x[3];
  for (int o = 32; o; o >>= 1) { s1 += __shfl_xor(s1, o); s2 += __shfl_xor(s2, o); }
  float mu = s1 * (1.f / 256.f);
  float var = s2 * (1.f / 256.f) - mu * mu;
  float inv = rsqrtf(var + 1e-5f);
#pragma unroll
  for (int i = 0; i < 4; i++)
    outp[base + i] = (x[i] - mu) * inv * g[lane * 4 + i] + b[lane * 4 + i];
}

__global__ void posnew_k(const float* __restrict__ pos, const float* __restrict__ cagg,
                         float* __restrict__ op) {
  int t = blockIdx.x * 256 + threadIdx.x;
  if (t >= NN * 3) return;
  op[t] = pos[t] + cagg[t];
}

// ---------------- feedback: S[row] += silu(dist_new*W_f1 + b_f1) -------------
__global__ __launch_bounds__(256) void edge_fb(const float* __restrict__ posn,
                                               const int* __restrict__ row,
                                               const int* __restrict__ colx,
                                               const float* __restrict__ Wf1,
                                               const float* __restrict__ bf1,
                                               float* __restrict__ S) {
  int w = threadIdx.x >> 6, lane = threadIdx.x & 63;
  int e = blockIdx.x * 4 + w;
  if (e >= EE) return;
  int r = row[e], c = colx[e];
  float d0 = posn[r * 3 + 0] - posn[c * 3 + 0];
  float d1 = posn[r * 3 + 1] - posn[c * 3 + 1];
  float d2 = posn[r * 3 + 2] - posn[c * 3 + 2];
  float dn = fmaxf(sqrtf(d0 * d0 + d1 * d1 + d2 * d2), 1e-5f);
  float* Sp = S + (size_t)r * 256 + lane * 4;
#pragma unroll
  for (int i = 0; i < 4; i++) {
    float xx = dn * Wf1[lane * 4 + i] + bf1[lane * 4 + i];
    atomicAdd(Sp + i, silu_f(xx));
  }
}

__global__ void cvt_bf(const float* __restrict__ src, u16* __restrict__ dst, int n) {
  int t = blockIdx.x * 256 + threadIdx.x;
  if (t < n) dst[t] = f2bf(src[t]);
}

extern "C" void kernel_launch(void* const* d_in, const int* in_sizes, int n_in,
                              void* d_out, int out_size, void* d_ws, size_t ws_size,
                              hipStream_t stream) {
  const float* h     = (const float*)d_in[0];
  const float* pos   = (const float*)d_in[1];
  const int*   eidx  = (const int*)d_in[2];
  const float* eattr = (const float*)d_in[3];
  const float* W_e1 = (const float*)d_in[4];  const float* b_e1 = (const float*)d_in[5];
  const float* g_e  = (const float*)d_in[6];  const float* be_ln = (const float*)d_in[7];
  const float* W_e2 = (const float*)d_in[8];  const float* b_e2 = (const float*)d_in[9];
  const float* W_n1 = (const float*)d_in[10]; const float* b_n1 = (const float*)d_in[11];
  const float* g_n  = (const float*)d_in[12]; const float* bn_ln = (const float*)d_in[13];
  const float* W_n2 = (const float*)d_in[14]; const float* b_n2 = (const float*)d_in[15];
  const float* g_o  = (const float*)d_in[16]; const float* bo_ln = (const float*)d_in[17];
  const float* W_c1 = (const float*)d_in[18]; const float* b_c1 = (const float*)d_in[19];
  const float* W_c2 = (const float*)d_in[20];
  const float* W_a  = (const float*)d_in[21]; const float* b_a = (const float*)d_in[22];
  const float* W_f1 = (const float*)d_in[23]; const float* b_f1 = (const float*)d_in[24];
  const float* W_f2 = (const float*)d_in[25]; const float* b_f2 = (const float*)d_in[26];

  float* outp = (float*)d_out;
  float* out_pos = outp + (size_t)NN * 256;

  char* base = (char*)d_ws;
  size_t off = 0;
  auto alloc = [&](size_t bytes) -> void* {
    off = (off + 255) & ~(size_t)255;
    void* p = base + off;
    off += bytes;
    return p;
  };
  // ---- persistent buffers (~57 MB) ----
  u16* We1T = (u16*)alloc((size_t)512 * 544 * 2);
  u16* We2T = (u16*)alloc((size_t)256 * 512 * 2);
  u16* Wn1T = (u16*)alloc((size_t)512 * 512 * 2);
  u16* Wn2T = (u16*)alloc((size_t)256 * 512 * 2);
  u16* Wc1T = (u16*)alloc((size_t)256 * 256 * 2);
  u16* Wf2T = (u16*)alloc((size_t)256 * 256 * 2);
  float* dist = (float*)alloc((size_t)EE * 4);
  float* cnt  = (float*)alloc((size_t)NN * 4);
  float* cagg = (float*)alloc((size_t)NN * 12);
  float* aggS = (float*)alloc((size_t)NN * 256 * 4);  // agg, later reused as S

  // ---- one adaptive arena, reused by all chunked phases ----
  off = (off + 255) & ~(size_t)255;
  char* arena = base + off;
  size_t avail = (ws_size > off) ? ws_size - off : 0;
  long ce = (long)(avail / 3136) & ~63L;   // 3136 B per edge in arena
  if (ce < 256) ce = 256;
  if (ce > 32768) ce = 32768;
  const int CE = (int)ce;
  u16* Ain  = (u16*)arena;                              // [CE][544] bf16
  u16* t1   = (u16*)(arena + (size_t)CE * 1088);        // [CE][512] bf16
  u16* mBuf = (u16*)(arena + (size_t)CE * 2112);        // [CE][256] bf16
  u16* c1   = (u16*)(arena + (size_t)CE * 2624);        // [CE][256] bf16
  long cnl = ((long)CE * 3136 / 3072) & ~63L;           // node chunk fits arena
  if (cnl > 8192) cnl = 8192;
  if (cnl < 64) cnl = 64;
  const int CNODE = (int)cnl;
  u16*   nodein = (u16*)arena;                          // [CN][512] bf16
  u16*   t2     = (u16*)(arena + (size_t)CNODE * 1024); // [CN][512] bf16
  float* hupd   = (float*)(arena + (size_t)CNODE * 2048); // [CN][256] f32
  u16*   Sbf    = (u16*)arena;                          // [CN][256] bf16

  hipMemsetAsync(cnt, 0, (size_t)NN * 4, stream);
  hipMemsetAsync(cagg, 0, (size_t)NN * 12, stream);
  hipMemsetAsync(aggS, 0, (size_t)NN * 256 * 4, stream);

  wtrans<<<(512 * 544 + 255) / 256, 256, 0, stream>>>(W_e1, We1T, 526, 512, 544);
  wtrans<<<(256 * 512 + 255) / 256, 256, 0, stream>>>(W_e2, We2T, 512, 256, 512);
  wtrans<<<(512 * 512 + 255) / 256, 256, 0, stream>>>(W_n1, Wn1T, 512, 512, 512);
  wtrans<<<(256 * 512 + 255) / 256, 256, 0, stream>>>(W_n2, Wn2T, 512, 256, 512);
  wtrans<<<(256 * 256 + 255) / 256, 256, 0, stream>>>(W_c1, Wc1T, 256, 256, 256);
  wtrans<<<(256 * 256 + 255) / 256, 256, 0, stream>>>(W_f2, Wf2T, 256, 256, 256);

  const int* rowp = eidx;
  const int* colp = eidx + EE;
  edge_geom<<<(EE + 255) / 256, 256, 0, stream>>>(pos, rowp, colp, dist, cnt);

  // ---- phase A: edge pipeline, chunked ----
  for (int e0 = 0; e0 < EE; e0 += CE) {
    int cc = EE - e0; if (cc > CE) cc = CE;
    build_ain<<<(cc * 544 + 255) / 256, 256, 0, stream>>>(h, rowp, colp, dist, eattr, Ain, e0, cc);
    dim3 g1((cc + 63) / 64, 8);
    gemm_k<0><<<g1, 256, 0, stream>>>(Ain, We1T, b_e1, t1, cc, 512, 544, nullptr, nullptr, 0.f);
    ln_512<<<cc, 128, 0, stream>>>(t1, g_e, be_ln);
    dim3 g2((cc + 63) / 64, 4);
    gemm_k<0><<<g2, 256, 0, stream>>>(t1, We2T, b_e2, mBuf, cc, 256, 512, nullptr, nullptr, 0.f);
    gemm_k<0><<<g2, 256, 0, stream>>>(mBuf, Wc1T, b_c1, c1, cc, 256, 256, nullptr, nullptr, 0.f);
    edge_scatter<<<(cc + 3) / 4, 256, 0, stream>>>(mBuf, c1, rowp, colp, pos, W_a, b_a, W_c2,
                                                   aggS, cagg, e0, cc);
  }

  // ---- phase B: node pipeline, chunked (reads aggS as agg) ----
  for (int n0 = 0; n0 < NN; n0 += CNODE) {
    int cn = NN - n0; if (cn > CNODE) cn = CNODE;
    build_nodein<<<(cn * 512 + 255) / 256, 256, 0, stream>>>(h + (size_t)n0 * 256,
                                                             aggS + (size_t)n0 * 256, nodein, cn);
    dim3 g4((cn + 63) / 64, 8);
    gemm_k<0><<<g4, 256, 0, stream>>>(nodein, Wn1T, b_n1, t2, cn, 512, 512, nullptr, nullptr, 0.f);
    ln_512<<<cn, 128, 0, stream>>>(t2, g_n, bn_ln);
    dim3 g5((cn + 63) / 64, 4);
    gemm_k<1><<<g5, 256, 0, stream>>>(t2, Wn2T, b_n2, hupd, cn, 256, 512, nullptr, nullptr, 0.f);
    hmid_ln<<<cn, 64, 0, stream>>>(h + (size_t)n0 * 256, hupd, g_o, bo_ln, outp + (size_t)n0 * 256);
  }

  // ---- phase C: coords + feedback (aggS reused as S) ----
  posnew_k<<<(NN * 3 + 255) / 256, 256, 0, stream>>>(pos, cagg, out_pos);
  hipMemsetAsync(aggS, 0, (size_t)NN * 256 * 4, stream);
  edge_fb<<<(EE + 3) / 4, 256, 0, stream>>>(out_pos, rowp, colp, W_f1, b_f1, aggS);
  for (int n0 = 0; n0 < NN; n0 += CNODE) {
    int cn = NN - n0; if (cn > CNODE) cn = CNODE;
    cvt_bf<<<(cn * 256 + 255) / 256, 256, 0, stream>>>(aggS + (size_t)n0 * 256, Sbf, cn * 256);
    dim3 g6((cn + 63) / 64, 4);
    gemm_k<2><<<g6, 256, 0, stream>>>(Sbf, Wf2T, nullptr, outp + (size_t)n0 * 256,
                                      cn, 256, 256, cnt + n0, b_f2, 0.1f);
  }
}

// Round 3
// 5969.376 us; speedup vs baseline: 1.6425x; 1.6425x over previous
//
#include <hip/hip_runtime.h>

// EGNN layer: N=50000 nodes, E=800000 edges, H=256.
// bf16 MFMA GEMMs; CSR (counting sort) so ALL segment-sums are direct
// per-node writes (no 256-wide f32 atomics). Node-aligned edge chunks with
// device-side counts (meta) keep the workspace bounded.

#define NN 50000
#define EE 800000

typedef unsigned short u16;
typedef float f32x4 __attribute__((ext_vector_type(4)));
typedef short bf16x8 __attribute__((ext_vector_type(8)));

__device__ __forceinline__ u16 f2bf(float f) {
  unsigned u = __float_as_uint(f);
  u = (u + 0x7FFFu + ((u >> 16) & 1u)) >> 16;
  return (u16)u;
}
__device__ __forceinline__ float bf2f(u16 s) {
  return __uint_as_float(((unsigned)s) << 16);
}
__device__ __forceinline__ float silu_f(float x) { return x / (1.f + __expf(-x)); }

// ---------------- generic MFMA GEMM: out = act(A[M,K] @ BT[N,K]^T + bias) ----
// MODE 0: silu -> bf16 ; MODE 1: none -> f32 ; MODE 2: f32 out += scale*(acc + cnt[m]*b2[n])
// M = meta ? meta[2*cidx+1] : Mh (device-side row count for edge chunks)
template <int MODE>
__global__ __launch_bounds__(256) void gemm_k(
    const u16* __restrict__ A, const u16* __restrict__ BT,
    const float* __restrict__ bias, void* __restrict__ outp,
    int Mh, int Nc, int K, const int* __restrict__ meta, int cidx,
    const float* __restrict__ cnt, const float* __restrict__ b2, float scale) {
  const int M = meta ? meta[2 * cidx + 1] : Mh;
  const int m0 = blockIdx.x * 64, n0 = blockIdx.y * 64;
  if (m0 >= M) return;
  __shared__ __align__(16) u16 As[64][32];
  __shared__ __align__(16) u16 Bs[64][32];
  const int tid = threadIdx.x;
  const int w = tid >> 6, lane = tid & 63;
  const int sr = tid >> 2, skc = (tid & 3) * 8;
  const int l15 = lane & 15, koff = (lane >> 4) * 8;

  f32x4 acc[4] = {};

  for (int k0 = 0; k0 < K; k0 += 32) {
    int ar = m0 + sr;
    uint4 av = make_uint4(0u, 0u, 0u, 0u);
    if (ar < M) av = *reinterpret_cast<const uint4*>(&A[(size_t)ar * K + k0 + skc]);
    *reinterpret_cast<uint4*>(&As[sr][skc]) = av;
    uint4 bv = *reinterpret_cast<const uint4*>(&BT[(size_t)(n0 + sr) * K + k0 + skc]);
    *reinterpret_cast<uint4*>(&Bs[sr][skc]) = bv;
    __syncthreads();
    bf16x8 a = *reinterpret_cast<const bf16x8*>(&As[16 * w + l15][koff]);
#pragma unroll
    for (int j = 0; j < 4; j++) {
      bf16x8 b = *reinterpret_cast<const bf16x8*>(&Bs[16 * j + l15][koff]);
      acc[j] = __builtin_amdgcn_mfma_f32_16x16x32_bf16(a, b, acc[j], 0, 0, 0);
    }
    __syncthreads();
  }

  const int rbase = m0 + 16 * w + ((lane >> 4) << 2);
#pragma unroll
  for (int j = 0; j < 4; j++) {
    int gc = n0 + 16 * j + l15;
    float bz = (MODE == 2) ? 0.f : bias[gc];
#pragma unroll
    for (int t = 0; t < 4; t++) {
      int gr = rbase + t;
      if (gr >= M) continue;
      size_t oi = (size_t)gr * Nc + gc;
      float v = acc[j][t] + bz;
      if (MODE == 0) {
        ((u16*)outp)[oi] = f2bf(silu_f(v));
      } else if (MODE == 1) {
        ((float*)outp)[oi] = v;
      } else {
        ((float*)outp)[oi] += scale * (v + cnt[gr] * b2[gc]);
      }
    }
  }
}

// ---------------- weight transpose + bf16 convert: src[K,N] -> dst[N,Kpad] ---
__global__ void wtrans(const float* __restrict__ src, u16* __restrict__ dst,
                       int K, int Nn, int Kpad) {
  int t = blockIdx.x * 256 + threadIdx.x;
  if (t >= Nn * Kpad) return;
  int n = t / Kpad, k = t - n * Kpad;
  float v = (k < K) ? src[(size_t)k * Nn + n] : 0.f;
  dst[t] = f2bf(v);
}

// ---------------- per-edge geometry + int degree count -----------------------
__global__ void edge_geom(const float* __restrict__ pos, const int* __restrict__ row,
                          const int* __restrict__ colx, float* __restrict__ dist,
                          int* __restrict__ icnt) {
  int e = blockIdx.x * 256 + threadIdx.x;
  if (e >= EE) return;
  int r = row[e], c = colx[e];
  float d0 = pos[r * 3 + 0] - pos[c * 3 + 0];
  float d1 = pos[r * 3 + 1] - pos[c * 3 + 1];
  float d2 = pos[r * 3 + 2] - pos[c * 3 + 2];
  dist[e] = fmaxf(sqrtf(d0 * d0 + d1 * d1 + d2 * d2), 1e-5f);
  atomicAdd(&icnt[r], 1);
}

// ---------------- single-block exclusive scan over 50k degrees ---------------
__global__ __launch_bounds__(1024) void scan_ptr(const int* __restrict__ icnt,
                                                 int* __restrict__ ptr) {
  __shared__ int ls[1024];
  const int t = threadIdx.x;
  const int SEG = (NN + 1023) / 1024;       // 49
  int s0 = t * SEG;
  int s1 = s0 + SEG; if (s1 > NN) s1 = NN;
  int sum = 0;
  for (int i = s0; i < s1; i++) sum += icnt[i];
  ls[t] = sum;
  __syncthreads();
  for (int off = 1; off < 1024; off <<= 1) {
    int v = (t >= off) ? ls[t - off] : 0;
    __syncthreads();
    ls[t] += v;
    __syncthreads();
  }
  int run = ls[t] - sum;                    // exclusive prefix for this segment
  for (int i = s0; i < s1; i++) { ptr[i] = run; run += icnt[i]; }
  if (t == 1023) ptr[NN] = ls[1023];
}

__global__ void copy_head(const int* __restrict__ ptr, int* __restrict__ head,
                          float* __restrict__ cntf) {
  int n = blockIdx.x * 256 + threadIdx.x;
  if (n >= NN) return;
  head[n] = ptr[n];
  cntf[n] = (float)(ptr[n + 1] - ptr[n]);
}

__global__ void fill_perm(const int* __restrict__ row, int* __restrict__ head,
                          int* __restrict__ perm) {
  int e = blockIdx.x * 256 + threadIdx.x;
  if (e >= EE) return;
  int p = atomicAdd(&head[row[e]], 1);
  perm[p] = e;
}

__global__ void chunk_meta(const int* __restrict__ ptr, int* __restrict__ meta,
                           int CN, int nch, int capE) {
  int c = blockIdx.x * 256 + threadIdx.x;
  if (c >= nch) return;
  int lo = c * CN;
  int hi = lo + CN; if (hi > NN) hi = NN;
  int b = ptr[lo];
  int cc = ptr[hi] - b;
  if (cc > capE) cc = capE;                 // safety clamp (should never hit)
  meta[2 * c + 0] = b;
  meta[2 * c + 1] = cc;
}

// ---------------- gather edge_in tile (CSR order) -> bf16 --------------------
__global__ void build_ain(const float* __restrict__ h, const int* __restrict__ row,
                          const int* __restrict__ colx, const float* __restrict__ dist,
                          const float* __restrict__ eattr, const int* __restrict__ perm,
                          const int* __restrict__ meta, int cidx,
                          u16* __restrict__ Ain) {
  int t = blockIdx.x * 256 + threadIdx.x;
  int le = t / 544, k = t - le * 544;
  if (le >= meta[2 * cidx + 1]) return;
  int e = perm[meta[2 * cidx] + le];
  float v = 0.f;
  if (k < 256) v = h[(size_t)row[e] * 256 + k];
  else if (k < 512) v = h[(size_t)colx[e] * 256 + (k - 256)];
  else if (k == 512) v = dist[e];
  else if (k < 526) v = eattr[(size_t)e * 13 + (k - 513)];
  Ain[t] = f2bf(v);
}

// ---------------- in-place row LayerNorm on bf16, D=512 ----------------------
__global__ __launch_bounds__(128) void ln_512(u16* __restrict__ t,
                                              const float* __restrict__ g,
                                              const float* __restrict__ b,
                                              int Mh, const int* __restrict__ meta, int cidx) {
  int row = blockIdx.x;
  if (row >= (meta ? meta[2 * cidx + 1] : Mh)) return;
  int tid = threadIdx.x;
  size_t base = (size_t)row * 512 + tid * 4;
  ushort4 xv = *reinterpret_cast<const ushort4*>(&t[base]);
  float x0 = bf2f(xv.x), x1 = bf2f(xv.y), x2 = bf2f(xv.z), x3 = bf2f(xv.w);
  float s1 = x0 + x1 + x2 + x3;
  float s2 = x0 * x0 + x1 * x1 + x2 * x2 + x3 * x3;
  for (int o = 32; o; o >>= 1) { s1 += __shfl_xor(s1, o); s2 += __shfl_xor(s2, o); }
  __shared__ float red[4];
  if ((tid & 63) == 0) { red[tid >> 6] = s1; red[2 + (tid >> 6)] = s2; }
  __syncthreads();
  s1 = red[0] + red[1]; s2 = red[2] + red[3];
  float mu = s1 * (1.f / 512.f);
  float var = s2 * (1.f / 512.f) - mu * mu;
  float inv = rsqrtf(var + 1e-5f);
  int c = tid * 4;
  ushort4 yv;
  yv.x = f2bf((x0 - mu) * inv * g[c + 0] + b[c + 0]);
  yv.y = f2bf((x1 - mu) * inv * g[c + 1] + b[c + 1]);
  yv.z = f2bf((x2 - mu) * inv * g[c + 2] + b[c + 2]);
  yv.w = f2bf((x3 - mu) * inv * g[c + 3] + b[c + 3]);
  *reinterpret_cast<ushort4*>(&t[base]) = yv;
}

// ---------------- per-edge dot products: att & coord weight ------------------
__global__ __launch_bounds__(256) void edge_dots(
    const u16* __restrict__ m, const u16* __restrict__ c1,
    const float* __restrict__ Wa, const float* __restrict__ ba,
    const float* __restrict__ Wc2,
    float* __restrict__ att, float* __restrict__ cw,
    const int* __restrict__ meta, int cidx) {
  int w = threadIdx.x >> 6, lane = threadIdx.x & 63;
  int le = blockIdx.x * 4 + w;
  if (le >= meta[2 * cidx + 1]) return;
  size_t mb = (size_t)le * 256 + lane * 4;
  float sa = 0.f, sc = 0.f;
#pragma unroll
  for (int i = 0; i < 4; i++) {
    sa += bf2f(m[mb + i]) * Wa[lane * 4 + i];
    sc += bf2f(c1[mb + i]) * Wc2[lane * 4 + i];
  }
  for (int o = 32; o; o >>= 1) { sa += __shfl_xor(sa, o); sc += __shfl_xor(sc, o); }
  if (lane == 0) {
    att[le] = 1.f / (1.f + __expf(-(sa + ba[0])));
    cw[le] = sc;
  }
}

// ---------------- per-node direct aggregation (no atomics) -------------------
__global__ __launch_bounds__(256) void node_agg(
    const u16* __restrict__ m, const float* __restrict__ att,
    const float* __restrict__ cw, const float* __restrict__ pos,
    const int* __restrict__ colx, const int* __restrict__ perm,
    const int* __restrict__ ptr, const int* __restrict__ meta, int cidx,
    float* __restrict__ agg, float* __restrict__ cagg, int nlo, int cn) {
  int w = threadIdx.x >> 6, lane = threadIdx.x & 63;
  int nl = blockIdx.x * 4 + w;
  if (nl >= cn) return;
  int n = nlo + nl;
  int base = meta[2 * cidx];
  int p0 = ptr[n], p1 = ptr[n + 1];
  float a0 = 0.f, a1 = 0.f, a2 = 0.f, a3 = 0.f;
  for (int p = p0; p < p1; p++) {
    float at = att[p - base];
    ushort4 mv = *reinterpret_cast<const ushort4*>(&m[(size_t)(p - base) * 256 + lane * 4]);
    a0 += at * bf2f(mv.x); a1 += at * bf2f(mv.y);
    a2 += at * bf2f(mv.z); a3 += at * bf2f(mv.w);
  }
  float* ag = agg + (size_t)n * 256 + lane * 4;
  ag[0] = a0; ag[1] = a1; ag[2] = a2; ag[3] = a3;
  if (lane < 3) {
    float pr = pos[n * 3 + lane], s = 0.f;
    for (int p = p0; p < p1; p++) {
      int c = colx[perm[p]];
      s += cw[p - base] * (pr - pos[c * 3 + lane]);
    }
    cagg[n * 3 + lane] = s;
  }
}

// ---------------- node_in chunk = [h | agg] -> bf16 --------------------------
__global__ void build_nodein(const float* __restrict__ h, const float* __restrict__ agg,
                             u16* __restrict__ ni, int cn) {
  int t = blockIdx.x * 256 + threadIdx.x;
  if (t >= cn * 512) return;
  int n = t >> 9, k = t & 511;
  float v = (k < 256) ? h[(size_t)n * 256 + k] : agg[(size_t)n * 256 + (k - 256)];
  ni[t] = f2bf(v);
}

// ---------------- final h LN ---------------------------------------------------
__global__ __launch_bounds__(64) void hmid_ln(const float* __restrict__ h,
                                              const float* __restrict__ hupd,
                                              const float* __restrict__ g,
                                              const float* __restrict__ b,
                                              float* __restrict__ outp) {
  int row = blockIdx.x, lane = threadIdx.x;
  size_t base = (size_t)row * 256 + lane * 4;
  float x[4];
#pragma unroll
  for (int i = 0; i < 4; i++) x[i] = h[base + i] + hupd[base + i];
  float s1 = x[0] + x[1] + x[2] + x[3];
  float s2 = x[0] * x[0] + x[1] * x[1] + x[2] * x[2] + x[3] * x[3];
  for (int o = 32; o; o >>= 1) { s1 += __shfl_xor(s1, o); s2 += __shfl_xor(s2, o); }
  float mu = s1 * (1.f / 256.f);
  float var = s2 * (1.f / 256.f) - mu * mu;
  float inv = rsqrtf(var + 1e-5f);
#pragma unroll
  for (int i = 0; i < 4; i++)
    outp[base + i] = (x[i] - mu) * inv * g[lane * 4 + i] + b[lane * 4 + i];
}

__global__ void posnew_k(const float* __restrict__ pos, const float* __restrict__ cagg,
                         float* __restrict__ op) {
  int t = blockIdx.x * 256 + threadIdx.x;
  if (t >= NN * 3) return;
  op[t] = pos[t] + cagg[t];
}

// ---------------- feedback via CSR: S[n] = sum_e silu(dn*Wf1+bf1), direct ----
__global__ __launch_bounds__(256) void edge_fb_csr(
    const float* __restrict__ posn, const int* __restrict__ colx,
    const int* __restrict__ perm, const int* __restrict__ ptr,
    const float* __restrict__ Wf1, const float* __restrict__ bf1,
    float* __restrict__ S) {
  int w = threadIdx.x >> 6, lane = threadIdx.x & 63;
  int n = blockIdx.x * 4 + w;
  if (n >= NN) return;
  float w0 = Wf1[lane * 4 + 0], w1 = Wf1[lane * 4 + 1];
  float w2 = Wf1[lane * 4 + 2], w3 = Wf1[lane * 4 + 3];
  float b0 = bf1[lane * 4 + 0], b1 = bf1[lane * 4 + 1];
  float b2 = bf1[lane * 4 + 2], b3 = bf1[lane * 4 + 3];
  float pr0 = posn[n * 3 + 0], pr1 = posn[n * 3 + 1], pr2 = posn[n * 3 + 2];
  float a0 = 0.f, a1 = 0.f, a2 = 0.f, a3 = 0.f;
  int p0 = ptr[n], p1 = ptr[n + 1];
  for (int p = p0; p < p1; p++) {
    int c = colx[perm[p]];
    float d0 = pr0 - posn[c * 3 + 0];
    float d1 = pr1 - posn[c * 3 + 1];
    float d2 = pr2 - posn[c * 3 + 2];
    float dn = fmaxf(sqrtf(d0 * d0 + d1 * d1 + d2 * d2), 1e-5f);
    a0 += silu_f(dn * w0 + b0);
    a1 += silu_f(dn * w1 + b1);
    a2 += silu_f(dn * w2 + b2);
    a3 += silu_f(dn * w3 + b3);
  }
  float* Sp = S + (size_t)n * 256 + lane * 4;
  Sp[0] = a0; Sp[1] = a1; Sp[2] = a2; Sp[3] = a3;
}

__global__ void cvt_bf(const float* __restrict__ src, u16* __restrict__ dst, int n) {
  int t = blockIdx.x * 256 + threadIdx.x;
  if (t < n) dst[t] = f2bf(src[t]);
}

extern "C" void kernel_launch(void* const* d_in, const int* in_sizes, int n_in,
                              void* d_out, int out_size, void* d_ws, size_t ws_size,
                              hipStream_t stream) {
  const float* h     = (const float*)d_in[0];
  const float* pos   = (const float*)d_in[1];
  const int*   eidx  = (const int*)d_in[2];
  const float* eattr = (const float*)d_in[3];
  const float* W_e1 = (const float*)d_in[4];  const float* b_e1 = (const float*)d_in[5];
  const float* g_e  = (const float*)d_in[6];  const float* be_ln = (const float*)d_in[7];
  const float* W_e2 = (const float*)d_in[8];  const float* b_e2 = (const float*)d_in[9];
  const float* W_n1 = (const float*)d_in[10]; const float* b_n1 = (const float*)d_in[11];
  const float* g_n  = (const float*)d_in[12]; const float* bn_ln = (const float*)d_in[13];
  const float* W_n2 = (const float*)d_in[14]; const float* b_n2 = (const float*)d_in[15];
  const float* g_o  = (const float*)d_in[16]; const float* bo_ln = (const float*)d_in[17];
  const float* W_c1 = (const float*)d_in[18]; const float* b_c1 = (const float*)d_in[19];
  const float* W_c2 = (const float*)d_in[20];
  const float* W_a  = (const float*)d_in[21]; const float* b_a = (const float*)d_in[22];
  const float* W_f1 = (const float*)d_in[23]; const float* b_f1 = (const float*)d_in[24];
  const float* W_f2 = (const float*)d_in[25]; const float* b_f2 = (const float*)d_in[26];

  float* outp = (float*)d_out;
  float* out_pos = outp + (size_t)NN * 256;

  char* base = (char*)d_ws;
  size_t off = 0;
  auto alloc = [&](size_t bytes) -> void* {
    off = (off + 255) & ~(size_t)255;
    void* p = base + off;
    off += bytes;
    return p;
  };
  // ---- persistent (~61 MB) ----
  u16* We1T = (u16*)alloc((size_t)512 * 544 * 2);
  u16* We2T = (u16*)alloc((size_t)256 * 512 * 2);
  u16* Wn1T = (u16*)alloc((size_t)512 * 512 * 2);
  u16* Wn2T = (u16*)alloc((size_t)256 * 512 * 2);
  u16* Wc1T = (u16*)alloc((size_t)256 * 256 * 2);
  u16* Wf2T = (u16*)alloc((size_t)256 * 256 * 2);
  float* dist = (float*)alloc((size_t)EE * 4);
  int*   icnt = (int*)alloc((size_t)NN * 4);
  int*   ptr  = (int*)alloc((size_t)(NN + 1) * 4);
  int*   head = (int*)alloc((size_t)NN * 4);
  int*   perm = (int*)alloc((size_t)EE * 4);
  float* cntf = (float*)alloc((size_t)NN * 4);
  float* cagg = (float*)alloc((size_t)NN * 12);
  int*   meta = (int*)alloc((size_t)8192);
  float* aggS = (float*)alloc((size_t)NN * 256 * 4);  // agg, reused as S

  // ---- adaptive node-chunk size ----
  off = (off + 255) & ~(size_t)255;
  char* arena = base + off;
  size_t avail = (ws_size > off) ? ws_size - off : 0;
  int CN = 2048;
  while (CN > 64 && (size_t)(CN * 16 + 4096) * 3144 > avail) CN >>= 1;
  const int capE = CN * 16 + 4096;
  u16*   Ain  = (u16*)arena;                                  // [capE][544]
  u16*   t1   = (u16*)(arena + (size_t)capE * 1088);          // [capE][512]
  u16*   mBuf = (u16*)(arena + (size_t)capE * 2112);          // [capE][256]
  u16*   c1   = (u16*)(arena + (size_t)capE * 2624);          // [capE][256]
  float* att  = (float*)(arena + (size_t)capE * 3136);        // [capE]
  float* cw   = (float*)(arena + (size_t)capE * 3140);        // [capE]
  long cnl = ((long)capE * 3144 / 3072) & ~63L;
  if (cnl > 8192) cnl = 8192;
  if (cnl < 64) cnl = 64;
  const int CNODE = (int)cnl;
  u16*   nodein = (u16*)arena;                                // [CNODE][512]
  u16*   t2     = (u16*)(arena + (size_t)CNODE * 1024);       // [CNODE][512]
  float* hupd   = (float*)(arena + (size_t)CNODE * 2048);     // [CNODE][256]
  u16*   Sbf    = (u16*)arena;                                // [CNODE][256]

  const int* rowp = eidx;
  const int* colp = eidx + EE;
  const int nch = (NN + CN - 1) / CN;

  hipMemsetAsync(icnt, 0, (size_t)NN * 4, stream);

  wtrans<<<(512 * 544 + 255) / 256, 256, 0, stream>>>(W_e1, We1T, 526, 512, 544);
  wtrans<<<(256 * 512 + 255) / 256, 256, 0, stream>>>(W_e2, We2T, 512, 256, 512);
  wtrans<<<(512 * 512 + 255) / 256, 256, 0, stream>>>(W_n1, Wn1T, 512, 512, 512);
  wtrans<<<(256 * 512 + 255) / 256, 256, 0, stream>>>(W_n2, Wn2T, 512, 256, 512);
  wtrans<<<(256 * 256 + 255) / 256, 256, 0, stream>>>(W_c1, Wc1T, 256, 256, 256);
  wtrans<<<(256 * 256 + 255) / 256, 256, 0, stream>>>(W_f2, Wf2T, 256, 256, 256);

  // ---- CSR build ----
  edge_geom<<<(EE + 255) / 256, 256, 0, stream>>>(pos, rowp, colp, dist, icnt);
  scan_ptr<<<1, 1024, 0, stream>>>(icnt, ptr);
  copy_head<<<(NN + 255) / 256, 256, 0, stream>>>(ptr, head, cntf);
  fill_perm<<<(EE + 255) / 256, 256, 0, stream>>>(rowp, head, perm);
  chunk_meta<<<(nch + 255) / 256, 256, 0, stream>>>(ptr, meta, CN, nch, capE);

  // ---- phase A: edge pipeline over node-aligned chunks ----
  for (int c = 0; c < nch; c++) {
    int nlo = c * CN;
    int cn = NN - nlo; if (cn > CN) cn = CN;
    build_ain<<<((size_t)capE * 544 + 255) / 256, 256, 0, stream>>>(
        h, rowp, colp, dist, eattr, perm, meta, c, Ain);
    dim3 g1((capE + 63) / 64, 8);
    gemm_k<0><<<g1, 256, 0, stream>>>(Ain, We1T, b_e1, t1, 0, 512, 544, meta, c, nullptr, nullptr, 0.f);
    ln_512<<<capE, 128, 0, stream>>>(t1, g_e, be_ln, 0, meta, c);
    dim3 g2((capE + 63) / 64, 4);
    gemm_k<0><<<g2, 256, 0, stream>>>(t1, We2T, b_e2, mBuf, 0, 256, 512, meta, c, nullptr, nullptr, 0.f);
    gemm_k<0><<<g2, 256, 0, stream>>>(mBuf, Wc1T, b_c1, c1, 0, 256, 256, meta, c, nullptr, nullptr, 0.f);
    edge_dots<<<(capE + 3) / 4, 256, 0, stream>>>(mBuf, c1, W_a, b_a, W_c2, att, cw, meta, c);
    node_agg<<<(cn + 3) / 4, 256, 0, stream>>>(mBuf, att, cw, pos, colp, perm, ptr, meta, c,
                                               aggS, cagg, nlo, cn);
  }

  // ---- phase B: node pipeline, chunked ----
  for (int n0 = 0; n0 < NN; n0 += CNODE) {
    int cn = NN - n0; if (cn > CNODE) cn = CNODE;
    build_nodein<<<(cn * 512 + 255) / 256, 256, 0, stream>>>(h + (size_t)n0 * 256,
                                                             aggS + (size_t)n0 * 256, nodein, cn);
    dim3 g4((cn + 63) / 64, 8);
    gemm_k<0><<<g4, 256, 0, stream>>>(nodein, Wn1T, b_n1, t2, cn, 512, 512, nullptr, 0, nullptr, nullptr, 0.f);
    ln_512<<<cn, 128, 0, stream>>>(t2, g_n, bn_ln, cn, nullptr, 0);
    dim3 g5((cn + 63) / 64, 4);
    gemm_k<1><<<g5, 256, 0, stream>>>(t2, Wn2T, b_n2, hupd, cn, 256, 512, nullptr, 0, nullptr, nullptr, 0.f);
    hmid_ln<<<cn, 64, 0, stream>>>(h + (size_t)n0 * 256, hupd, g_o, bo_ln, outp + (size_t)n0 * 256);
  }

  // ---- phase C: coords + feedback (aggS reused as S, direct writes) ----
  posnew_k<<<(NN * 3 + 255) / 256, 256, 0, stream>>>(pos, cagg, out_pos);
  edge_fb_csr<<<(NN + 3) / 4, 256, 0, stream>>>(out_pos, colp, perm, ptr, W_f1, b_f1, aggS);
  for (int n0 = 0; n0 < NN; n0 += CNODE) {
    int cn = NN - n0; if (cn > CNODE) cn = CNODE;
    cvt_bf<<<(cn * 256 + 255) / 256, 256, 0, stream>>>(aggS + (size_t)n0 * 256, Sbf, cn * 256);
    dim3 g6((cn + 63) / 64, 4);
    gemm_k<2><<<g6, 256, 0, stream>>>(Sbf, Wf2T, nullptr, outp + (size_t)n0 * 256,
                                      cn, 256, 256, nullptr, 0, cntf + n0, b_f2, 0.1f);
  }
}

// Round 4
// 5132.056 us; speedup vs baseline: 1.9105x; 1.1632x over previous
//
#include <hip/hip_runtime.h>

// EGNN layer: N=50000 nodes, E=800000 edges, H=256.
// Round 4: m97-structure GEMM (128x128 tile, global_load_lds width=16,
// 4 waves, acc[4][4]) + edge GEMM fuses the [h_row|h_col|dist|eattr] gather
// directly into LDS staging (per-lane global addresses), deleting build_ain.
// CSR keeps all segment-sums atomic-free.

#define NN 50000
#define EE 800000

typedef unsigned short u16;
typedef float f32x4 __attribute__((ext_vector_type(4)));
typedef short bf16x8 __attribute__((ext_vector_type(8)));

__device__ __forceinline__ u16 f2bf(float f) {
  unsigned u = __float_as_uint(f);
  u = (u + 0x7FFFu + ((u >> 16) & 1u)) >> 16;
  return (u16)u;
}
__device__ __forceinline__ float bf2f(u16 s) {
  return __uint_as_float(((unsigned)s) << 16);
}
__device__ __forceinline__ float silu_f(float x) { return x / (1.f + __expf(-x)); }

// async global->LDS, 16B per lane; LDS dest = base + lane*16 (HW), global addr per-lane
__device__ __forceinline__ void gload16(const void* g, void* l) {
  __builtin_amdgcn_global_load_lds(
      (const __attribute__((address_space(1))) void*)g,
      (__attribute__((address_space(3))) void*)l, 16, 0, 0);
}

// ---------------- 128x128 MFMA GEMM (m97 structure) --------------------------
// out = act(A[M,K] @ BT[N,K]^T + bias)
// MODE 0: silu -> bf16 ; MODE 1: none -> f32 ; MODE 2: f32 out += scale*(acc + cnt[m]*b2[n])
// GATHER 1: A row le is edge perm[meta[2c]+le]: cols [0,256)=hbf[row[e]],
//           [256,512)=hbf[col[e]], [512,544)=tail[le][0..32)
template <int MODE, int GATHER>
__global__ __launch_bounds__(256) void gemm128(
    const u16* __restrict__ A, const u16* __restrict__ BT,
    const float* __restrict__ bias, void* __restrict__ outp,
    int Mh, int Nc, int K, const int* __restrict__ meta, int cidx,
    const u16* __restrict__ hbf, const int* __restrict__ rowp,
    const int* __restrict__ colp, const int* __restrict__ perm,
    const u16* __restrict__ tail,
    const float* __restrict__ cnt, const float* __restrict__ b2, float scale) {
  const int M = meta ? meta[2 * cidx + 1] : Mh;
  const int m0 = blockIdx.x * 128, n0 = blockIdx.y * 128;
  if (m0 >= M) return;
  __shared__ __align__(16) u16 As[128][32];
  __shared__ __align__(16) u16 Bs[128][32];
  const int tid = threadIdx.x, w = tid >> 6, lane = tid & 63;
  const int srow = lane >> 2, sch = (lane & 3) * 8;  // staging: row-in-seg, elem offset
  const int r0 = w * 32 + srow, r1 = r0 + 16;

  u16* as0 = &As[w * 32][0];
  u16* as1 = &As[w * 32 + 16][0];
  u16* bs0 = &Bs[w * 32][0];
  u16* bs1 = &Bs[w * 32 + 16][0];

  const u16 *a0r, *a0c, *a0t, *a1r, *a1c, *a1t;
  if (GATHER) {
    const int eb = meta[2 * cidx];
    int le0 = m0 + r0; if (le0 > M - 1) le0 = M - 1;
    int le1 = m0 + r1; if (le1 > M - 1) le1 = M - 1;
    const int e0 = perm[eb + le0], e1 = perm[eb + le1];
    a0r = hbf + (size_t)rowp[e0] * 256; a0c = hbf + (size_t)colp[e0] * 256;
    a1r = hbf + (size_t)rowp[e1] * 256; a1c = hbf + (size_t)colp[e1] * 256;
    a0t = tail + (size_t)le0 * 32;      a1t = tail + (size_t)le1 * 32;
  } else {
    a0r = A + (size_t)(m0 + r0) * K;
    a1r = A + (size_t)(m0 + r1) * K;
    a0c = a0t = a1c = a1t = nullptr;
  }
  const u16* b0 = BT + (size_t)(n0 + r0) * K;
  const u16* b1 = BT + (size_t)(n0 + r1) * K;

  f32x4 acc[4][4] = {};
  const int l15 = lane & 15, ko = (lane >> 4) * 8;
  const int ar0 = (w >> 1) * 64, br0 = (w & 1) * 64;

  for (int k0 = 0; k0 < K; k0 += 32) {
    const u16 *pa0, *pa1;
    if (GATHER) {
      if (k0 < 256)      { pa0 = a0r + k0;         pa1 = a1r + k0; }
      else if (k0 < 512) { pa0 = a0c + (k0 - 256); pa1 = a1c + (k0 - 256); }
      else               { pa0 = a0t;              pa1 = a1t; }
    } else { pa0 = a0r + k0; pa1 = a1r + k0; }
    gload16(pa0 + sch, as0);
    gload16(pa1 + sch, as1);
    gload16(b0 + k0 + sch, bs0);
    gload16(b1 + k0 + sch, bs1);
    __syncthreads();
    bf16x8 af[4], bfr[4];
#pragma unroll
    for (int i = 0; i < 4; i++)
      af[i] = *reinterpret_cast<const bf16x8*>(&As[ar0 + i * 16 + l15][ko]);
#pragma unroll
    for (int j = 0; j < 4; j++)
      bfr[j] = *reinterpret_cast<const bf16x8*>(&Bs[br0 + j * 16 + l15][ko]);
#pragma unroll
    for (int i = 0; i < 4; i++)
#pragma unroll
      for (int j = 0; j < 4; j++)
        acc[i][j] = __builtin_amdgcn_mfma_f32_16x16x32_bf16(af[i], bfr[j], acc[i][j], 0, 0, 0);
    __syncthreads();
  }

  const int rb = m0 + ar0 + ((lane >> 4) << 2);
#pragma unroll
  for (int j = 0; j < 4; j++) {
    const int gc = n0 + br0 + j * 16 + l15;
    const float bz = (MODE == 2) ? 0.f : bias[gc];
#pragma unroll
    for (int i = 0; i < 4; i++) {
#pragma unroll
      for (int t = 0; t < 4; t++) {
        const int gr = rb + i * 16 + t;
        if (gr >= M) continue;
        size_t oi = (size_t)gr * Nc + gc;
        float v = acc[i][j][t] + bz;
        if (MODE == 0)      ((u16*)outp)[oi] = f2bf(silu_f(v));
        else if (MODE == 1) ((float*)outp)[oi] = v;
        else                ((float*)outp)[oi] += scale * (v + cnt[gr] * b2[gc]);
      }
    }
  }
}

// ---------------- weight transpose + bf16 convert: src[K,N] -> dst[N,Kpad] ---
__global__ void wtrans(const float* __restrict__ src, u16* __restrict__ dst,
                       int K, int Nn, int Kpad) {
  int t = blockIdx.x * 256 + threadIdx.x;
  if (t >= Nn * Kpad) return;
  int n = t / Kpad, k = t - n * Kpad;
  float v = (k < K) ? src[(size_t)k * Nn + n] : 0.f;
  dst[t] = f2bf(v);
}

// ---------------- per-edge geometry + int degree count -----------------------
__global__ void edge_geom(const float* __restrict__ pos, const int* __restrict__ row,
                          const int* __restrict__ colx, float* __restrict__ dist,
                          int* __restrict__ icnt) {
  int e = blockIdx.x * 256 + threadIdx.x;
  if (e >= EE) return;
  int r = row[e], c = colx[e];
  float d0 = pos[r * 3 + 0] - pos[c * 3 + 0];
  float d1 = pos[r * 3 + 1] - pos[c * 3 + 1];
  float d2 = pos[r * 3 + 2] - pos[c * 3 + 2];
  dist[e] = fmaxf(sqrtf(d0 * d0 + d1 * d1 + d2 * d2), 1e-5f);
  atomicAdd(&icnt[r], 1);
}

// ---------------- single-block exclusive scan over 50k degrees ---------------
__global__ __launch_bounds__(1024) void scan_ptr(const int* __restrict__ icnt,
                                                 int* __restrict__ ptr) {
  __shared__ int ls[1024];
  const int t = threadIdx.x;
  const int SEG = (NN + 1023) / 1024;
  int s0 = t * SEG;
  int s1 = s0 + SEG; if (s1 > NN) s1 = NN;
  int sum = 0;
  for (int i = s0; i < s1; i++) sum += icnt[i];
  ls[t] = sum;
  __syncthreads();
  for (int off = 1; off < 1024; off <<= 1) {
    int v = (t >= off) ? ls[t - off] : 0;
    __syncthreads();
    ls[t] += v;
    __syncthreads();
  }
  int run = ls[t] - sum;
  for (int i = s0; i < s1; i++) { ptr[i] = run; run += icnt[i]; }
  if (t == 1023) ptr[NN] = ls[1023];
}

__global__ void copy_head(const int* __restrict__ ptr, int* __restrict__ head,
                          float* __restrict__ cntf) {
  int n = blockIdx.x * 256 + threadIdx.x;
  if (n >= NN) return;
  head[n] = ptr[n];
  cntf[n] = (float)(ptr[n + 1] - ptr[n]);
}

__global__ void fill_perm(const int* __restrict__ row, int* __restrict__ head,
                          int* __restrict__ perm) {
  int e = blockIdx.x * 256 + threadIdx.x;
  if (e >= EE) return;
  int p = atomicAdd(&head[row[e]], 1);
  perm[p] = e;
}

__global__ void chunk_meta(const int* __restrict__ ptr, int* __restrict__ meta,
                           int CN, int nch, int capE) {
  int c = blockIdx.x * 256 + threadIdx.x;
  if (c >= nch) return;
  int lo = c * CN;
  int hi = lo + CN; if (hi > NN) hi = NN;
  int b = ptr[lo];
  int cc = ptr[hi] - b;
  if (cc > capE) cc = capE;
  meta[2 * c + 0] = b;
  meta[2 * c + 1] = cc;
}

// ---------------- tail cols [dist | eattr*13 | 0-pad] for edge GEMM ----------
__global__ void build_tail(const float* __restrict__ dist, const float* __restrict__ eattr,
                           const int* __restrict__ perm, const int* __restrict__ meta,
                           int cidx, u16* __restrict__ tail, int capE) {
  int t = blockIdx.x * 256 + threadIdx.x;
  if (t >= capE * 32) return;
  int le = t >> 5, j = t & 31;
  if (le >= meta[2 * cidx + 1]) return;
  int e = perm[meta[2 * cidx] + le];
  float v = 0.f;
  if (j == 0) v = dist[e];
  else if (j < 14) v = eattr[(size_t)e * 13 + (j - 1)];
  tail[t] = f2bf(v);
}

// ---------------- in-place row LayerNorm on bf16, D=512 ----------------------
__global__ __launch_bounds__(128) void ln_512(u16* __restrict__ t,
                                              const float* __restrict__ g,
                                              const float* __restrict__ b,
                                              int Mh, const int* __restrict__ meta, int cidx) {
  int row = blockIdx.x;
  if (row >= (meta ? meta[2 * cidx + 1] : Mh)) return;
  int tid = threadIdx.x;
  size_t base = (size_t)row * 512 + tid * 4;
  ushort4 xv = *reinterpret_cast<const ushort4*>(&t[base]);
  float x0 = bf2f(xv.x), x1 = bf2f(xv.y), x2 = bf2f(xv.z), x3 = bf2f(xv.w);
  float s1 = x0 + x1 + x2 + x3;
  float s2 = x0 * x0 + x1 * x1 + x2 * x2 + x3 * x3;
  for (int o = 32; o; o >>= 1) { s1 += __shfl_xor(s1, o); s2 += __shfl_xor(s2, o); }
  __shared__ float red[4];
  if ((tid & 63) == 0) { red[tid >> 6] = s1; red[2 + (tid >> 6)] = s2; }
  __syncthreads();
  s1 = red[0] + red[1]; s2 = red[2] + red[3];
  float mu = s1 * (1.f / 512.f);
  float var = s2 * (1.f / 512.f) - mu * mu;
  float inv = rsqrtf(var + 1e-5f);
  int c = tid * 4;
  ushort4 yv;
  yv.x = f2bf((x0 - mu) * inv * g[c + 0] + b[c + 0]);
  yv.y = f2bf((x1 - mu) * inv * g[c + 1] + b[c + 1]);
  yv.z = f2bf((x2 - mu) * inv * g[c + 2] + b[c + 2]);
  yv.w = f2bf((x3 - mu) * inv * g[c + 3] + b[c + 3]);
  *reinterpret_cast<ushort4*>(&t[base]) = yv;
}

// ---------------- per-edge dot products: att & coord weight ------------------
__global__ __launch_bounds__(256) void edge_dots(
    const u16* __restrict__ m, const u16* __restrict__ c1,
    const float* __restrict__ Wa, const float* __restrict__ ba,
    const float* __restrict__ Wc2,
    float* __restrict__ att, float* __restrict__ cw,
    const int* __restrict__ meta, int cidx) {
  int w = threadIdx.x >> 6, lane = threadIdx.x & 63;
  int le = blockIdx.x * 4 + w;
  if (le >= meta[2 * cidx + 1]) return;
  size_t mb = (size_t)le * 256 + lane * 4;
  float sa = 0.f, sc = 0.f;
#pragma unroll
  for (int i = 0; i < 4; i++) {
    sa += bf2f(m[mb + i]) * Wa[lane * 4 + i];
    sc += bf2f(c1[mb + i]) * Wc2[lane * 4 + i];
  }
  for (int o = 32; o; o >>= 1) { sa += __shfl_xor(sa, o); sc += __shfl_xor(sc, o); }
  if (lane == 0) {
    att[le] = 1.f / (1.f + __expf(-(sa + ba[0])));
    cw[le] = sc;
  }
}

// ---------------- per-node direct aggregation (no atomics) -------------------
__global__ __launch_bounds__(256) void node_agg(
    const u16* __restrict__ m, const float* __restrict__ att,
    const float* __restrict__ cw, const float* __restrict__ pos,
    const int* __restrict__ colx, const int* __restrict__ perm,
    const int* __restrict__ ptr, const int* __restrict__ meta, int cidx,
    float* __restrict__ agg, float* __restrict__ cagg, int nlo, int cn) {
  int w = threadIdx.x >> 6, lane = threadIdx.x & 63;
  int nl = blockIdx.x * 4 + w;
  if (nl >= cn) return;
  int n = nlo + nl;
  int base = meta[2 * cidx];
  int p0 = ptr[n], p1 = ptr[n + 1];
  float a0 = 0.f, a1 = 0.f, a2 = 0.f, a3 = 0.f;
  for (int p = p0; p < p1; p++) {
    float at = att[p - base];
    ushort4 mv = *reinterpret_cast<const ushort4*>(&m[(size_t)(p - base) * 256 + lane * 4]);
    a0 += at * bf2f(mv.x); a1 += at * bf2f(mv.y);
    a2 += at * bf2f(mv.z); a3 += at * bf2f(mv.w);
  }
  float* ag = agg + (size_t)n * 256 + lane * 4;
  ag[0] = a0; ag[1] = a1; ag[2] = a2; ag[3] = a3;
  if (lane < 3) {
    float pr = pos[n * 3 + lane], s = 0.f;
    for (int p = p0; p < p1; p++) {
      int c = colx[perm[p]];
      s += cw[p - base] * (pr - pos[c * 3 + lane]);
    }
    cagg[n * 3 + lane] = s;
  }
}

// ---------------- node_in chunk = [h | agg] -> bf16 --------------------------
__global__ void build_nodein(const float* __restrict__ h, const float* __restrict__ agg,
                             u16* __restrict__ ni, int cn) {
  int t = blockIdx.x * 256 + threadIdx.x;
  if (t >= cn * 512) return;
  int n = t >> 9, k = t & 511;
  float v = (k < 256) ? h[(size_t)n * 256 + k] : agg[(size_t)n * 256 + (k - 256)];
  ni[t] = f2bf(v);
}

// ---------------- final h LN --------------------------------------------------
__global__ __launch_bounds__(64) void hmid_ln(const float* __restrict__ h,
                                              const float* __restrict__ hupd,
                                              const float* __restrict__ g,
                                              const float* __restrict__ b,
                                              float* __restrict__ outp) {
  int row = blockIdx.x, lane = threadIdx.x;
  size_t base = (size_t)row * 256 + lane * 4;
  float x[4];
#pragma unroll
  for (int i = 0; i < 4; i++) x[i] = h[base + i] + hupd[base + i];
  float s1 = x[0] + x[1] + x[2] + x[3];
  float s2 = x[0] * x[0] + x[1] * x[1] + x[2] * x[2] + x[3] * x[3];
  for (int o = 32; o; o >>= 1) { s1 += __shfl_xor(s1, o); s2 += __shfl_xor(s2, o); }
  float mu = s1 * (1.f / 256.f);
  float var = s2 * (1.f / 256.f) - mu * mu;
  float inv = rsqrtf(var + 1e-5f);
#pragma unroll
  for (int i = 0; i < 4; i++)
    outp[base + i] = (x[i] - mu) * inv * g[lane * 4 + i] + b[lane * 4 + i];
}

__global__ void posnew_k(const float* __restrict__ pos, const float* __restrict__ cagg,
                         float* __restrict__ op) {
  int t = blockIdx.x * 256 + threadIdx.x;
  if (t >= NN * 3) return;
  op[t] = pos[t] + cagg[t];
}

// ---------------- feedback via CSR: S[n] = sum_e silu(dn*Wf1+bf1), direct ----
__global__ __launch_bounds__(256) void edge_fb_csr(
    const float* __restrict__ posn, const int* __restrict__ colx,
    const int* __restrict__ perm, const int* __restrict__ ptr,
    const float* __restrict__ Wf1, const float* __restrict__ bf1,
    float* __restrict__ S) {
  int w = threadIdx.x >> 6, lane = threadIdx.x & 63;
  int n = blockIdx.x * 4 + w;
  if (n >= NN) return;
  float w0 = Wf1[lane * 4 + 0], w1 = Wf1[lane * 4 + 1];
  float w2 = Wf1[lane * 4 + 2], w3 = Wf1[lane * 4 + 3];
  float b0 = bf1[lane * 4 + 0], b1 = bf1[lane * 4 + 1];
  float b2 = bf1[lane * 4 + 2], b3 = bf1[lane * 4 + 3];
  float pr0 = posn[n * 3 + 0], pr1 = posn[n * 3 + 1], pr2 = posn[n * 3 + 2];
  float a0 = 0.f, a1 = 0.f, a2 = 0.f, a3 = 0.f;
  int p0 = ptr[n], p1 = ptr[n + 1];
  for (int p = p0; p < p1; p++) {
    int c = colx[perm[p]];
    float d0 = pr0 - posn[c * 3 + 0];
    float d1 = pr1 - posn[c * 3 + 1];
    float d2 = pr2 - posn[c * 3 + 2];
    float dn = fmaxf(sqrtf(d0 * d0 + d1 * d1 + d2 * d2), 1e-5f);
    a0 += silu_f(dn * w0 + b0);
    a1 += silu_f(dn * w1 + b1);
    a2 += silu_f(dn * w2 + b2);
    a3 += silu_f(dn * w3 + b3);
  }
  float* Sp = S + (size_t)n * 256 + lane * 4;
  Sp[0] = a0; Sp[1] = a1; Sp[2] = a2; Sp[3] = a3;
}

__global__ void cvt_bf(const float* __restrict__ src, u16* __restrict__ dst, int n) {
  int t = blockIdx.x * 256 + threadIdx.x;
  if (t < n) dst[t] = f2bf(src[t]);
}

extern "C" void kernel_launch(void* const* d_in, const int* in_sizes, int n_in,
                              void* d_out, int out_size, void* d_ws, size_t ws_size,
                              hipStream_t stream) {
  const float* h     = (const float*)d_in[0];
  const float* pos   = (const float*)d_in[1];
  const int*   eidx  = (const int*)d_in[2];
  const float* eattr = (const float*)d_in[3];
  const float* W_e1 = (const float*)d_in[4];  const float* b_e1 = (const float*)d_in[5];
  const float* g_e  = (const float*)d_in[6];  const float* be_ln = (const float*)d_in[7];
  const float* W_e2 = (const float*)d_in[8];  const float* b_e2 = (const float*)d_in[9];
  const float* W_n1 = (const float*)d_in[10]; const float* b_n1 = (const float*)d_in[11];
  const float* g_n  = (const float*)d_in[12]; const float* bn_ln = (const float*)d_in[13];
  const float* W_n2 = (const float*)d_in[14]; const float* b_n2 = (const float*)d_in[15];
  const float* g_o  = (const float*)d_in[16]; const float* bo_ln = (const float*)d_in[17];
  const float* W_c1 = (const float*)d_in[18]; const float* b_c1 = (const float*)d_in[19];
  const float* W_c2 = (const float*)d_in[20];
  const float* W_a  = (const float*)d_in[21]; const float* b_a = (const float*)d_in[22];
  const float* W_f1 = (const float*)d_in[23]; const float* b_f1 = (const float*)d_in[24];
  const float* W_f2 = (const float*)d_in[25]; const float* b_f2 = (const float*)d_in[26];

  float* outp = (float*)d_out;
  float* out_pos = outp + (size_t)NN * 256;

  char* base = (char*)d_ws;
  size_t off = 0;
  auto alloc = [&](size_t bytes) -> void* {
    off = (off + 255) & ~(size_t)255;
    void* p = base + off;
    off += bytes;
    return p;
  };
  // ---- persistent (~87 MB) ----
  u16* We1T = (u16*)alloc((size_t)512 * 544 * 2);
  u16* We2T = (u16*)alloc((size_t)256 * 512 * 2);
  u16* Wn1T = (u16*)alloc((size_t)512 * 512 * 2);
  u16* Wn2T = (u16*)alloc((size_t)256 * 512 * 2);
  u16* Wc1T = (u16*)alloc((size_t)256 * 256 * 2);
  u16* Wf2T = (u16*)alloc((size_t)256 * 256 * 2);
  u16* hbf  = (u16*)alloc((size_t)NN * 256 * 2);      // h in bf16 for gather-GEMM
  float* dist = (float*)alloc((size_t)EE * 4);
  int*   icnt = (int*)alloc((size_t)NN * 4);
  int*   ptr  = (int*)alloc((size_t)(NN + 1) * 4);
  int*   head = (int*)alloc((size_t)NN * 4);
  int*   perm = (int*)alloc((size_t)EE * 4);
  float* cntf = (float*)alloc((size_t)NN * 4);
  float* cagg = (float*)alloc((size_t)NN * 12);
  int*   meta = (int*)alloc((size_t)8192);
  float* aggS = (float*)alloc((size_t)NN * 256 * 4);  // agg, reused as S

  // ---- adaptive node-chunk size; arena 2120 B/edge ----
  off = (off + 255) & ~(size_t)255;
  char* arena = base + off;
  size_t avail = (ws_size > off) ? ws_size - off : 0;
  int CN = 2048;
  while (CN > 64 && (size_t)(CN * 16 + 4096) * 2120 > avail) CN >>= 1;
  const int capE = CN * 16 + 4096;                    // multiple of 128
  u16*   t1   = (u16*)arena;                          // [capE][512]
  u16*   mBuf = (u16*)(arena + (size_t)capE * 1024);  // [capE][256]
  u16*   c1   = (u16*)(arena + (size_t)capE * 1536);  // [capE][256]
  u16*   tail = (u16*)(arena + (size_t)capE * 2048);  // [capE][32]
  float* att  = (float*)(arena + (size_t)capE * 2112);// [capE]
  float* cw   = (float*)(arena + (size_t)capE * 2116);// [capE]
  long cnl = ((long)capE * 2120 / 3072) & ~127L;
  if (cnl > 8192) cnl = 8192;
  if (cnl < 128) cnl = 128;
  const int CNODE = (int)cnl;
  u16*   nodein = (u16*)arena;                           // [CNODE][512]
  u16*   t2     = (u16*)(arena + (size_t)CNODE * 1024);  // [CNODE][512]
  float* hupd   = (float*)(arena + (size_t)CNODE * 2048);// [CNODE][256]
  u16*   Sbf    = (u16*)arena;                           // [CNODE][256]

  const int* rowp = eidx;
  const int* colp = eidx + EE;
  const int nch = (NN + CN - 1) / CN;

  hipMemsetAsync(icnt, 0, (size_t)NN * 4, stream);

  wtrans<<<(512 * 544 + 255) / 256, 256, 0, stream>>>(W_e1, We1T, 526, 512, 544);
  wtrans<<<(256 * 512 + 255) / 256, 256, 0, stream>>>(W_e2, We2T, 512, 256, 512);
  wtrans<<<(512 * 512 + 255) / 256, 256, 0, stream>>>(W_n1, Wn1T, 512, 512, 512);
  wtrans<<<(256 * 512 + 255) / 256, 256, 0, stream>>>(W_n2, Wn2T, 512, 256, 512);
  wtrans<<<(256 * 256 + 255) / 256, 256, 0, stream>>>(W_c1, Wc1T, 256, 256, 256);
  wtrans<<<(256 * 256 + 255) / 256, 256, 0, stream>>>(W_f2, Wf2T, 256, 256, 256);
  cvt_bf<<<(NN * 256 + 255) / 256, 256, 0, stream>>>(h, hbf, NN * 256);

  // ---- CSR build ----
  edge_geom<<<(EE + 255) / 256, 256, 0, stream>>>(pos, rowp, colp, dist, icnt);
  scan_ptr<<<1, 1024, 0, stream>>>(icnt, ptr);
  copy_head<<<(NN + 255) / 256, 256, 0, stream>>>(ptr, head, cntf);
  fill_perm<<<(EE + 255) / 256, 256, 0, stream>>>(rowp, head, perm);
  chunk_meta<<<(nch + 255) / 256, 256, 0, stream>>>(ptr, meta, CN, nch, capE);

  // ---- phase A: edge pipeline over node-aligned chunks ----
  for (int c = 0; c < nch; c++) {
    int nlo = c * CN;
    int cn = NN - nlo; if (cn > CN) cn = CN;
    build_tail<<<(capE * 32 + 255) / 256, 256, 0, stream>>>(dist, eattr, perm, meta, c, tail, capE);
    dim3 g1(capE / 128, 4);
    gemm128<0, 1><<<g1, 256, 0, stream>>>(nullptr, We1T, b_e1, t1, 0, 512, 544, meta, c,
                                          hbf, rowp, colp, perm, tail, nullptr, nullptr, 0.f);
    ln_512<<<capE, 128, 0, stream>>>(t1, g_e, be_ln, 0, meta, c);
    dim3 g2(capE / 128, 2);
    gemm128<0, 0><<<g2, 256, 0, stream>>>(t1, We2T, b_e2, mBuf, 0, 256, 512, meta, c,
                                          nullptr, nullptr, nullptr, nullptr, nullptr, nullptr, nullptr, 0.f);
    gemm128<0, 0><<<g2, 256, 0, stream>>>(mBuf, Wc1T, b_c1, c1, 0, 256, 256, meta, c,
                                          nullptr, nullptr, nullptr, nullptr, nullptr, nullptr, nullptr, 0.f);
    edge_dots<<<(capE + 3) / 4, 256, 0, stream>>>(mBuf, c1, W_a, b_a, W_c2, att, cw, meta, c);
    node_agg<<<(cn + 3) / 4, 256, 0, stream>>>(mBuf, att, cw, pos, colp, perm, ptr, meta, c,
                                               aggS, cagg, nlo, cn);
  }

  // ---- phase B: node pipeline, chunked ----
  for (int n0 = 0; n0 < NN; n0 += CNODE) {
    int cn = NN - n0; if (cn > CNODE) cn = CNODE;
    build_nodein<<<(cn * 512 + 255) / 256, 256, 0, stream>>>(h + (size_t)n0 * 256,
                                                             aggS + (size_t)n0 * 256, nodein, cn);
    dim3 g4((cn + 127) / 128, 4);
    gemm128<0, 0><<<g4, 256, 0, stream>>>(nodein, Wn1T, b_n1, t2, cn, 512, 512, nullptr, 0,
                                          nullptr, nullptr, nullptr, nullptr, nullptr, nullptr, nullptr, 0.f);
    ln_512<<<cn, 128, 0, stream>>>(t2, g_n, bn_ln, cn, nullptr, 0);
    dim3 g5((cn + 127) / 128, 2);
    gemm128<1, 0><<<g5, 256, 0, stream>>>(t2, Wn2T, b_n2, hupd, cn, 256, 512, nullptr, 0,
                                          nullptr, nullptr, nullptr, nullptr, nullptr, nullptr, nullptr, 0.f);
    hmid_ln<<<cn, 64, 0, stream>>>(h + (size_t)n0 * 256, hupd, g_o, bo_ln, outp + (size_t)n0 * 256);
  }

  // ---- phase C: coords + feedback (aggS reused as S, direct writes) ----
  posnew_k<<<(NN * 3 + 255) / 256, 256, 0, stream>>>(pos, cagg, out_pos);
  edge_fb_csr<<<(NN + 3) / 4, 256, 0, stream>>>(out_pos, colp, perm, ptr, W_f1, b_f1, aggS);
  for (int n0 = 0; n0 < NN; n0 += CNODE) {
    int cn = NN - n0; if (cn > CNODE) cn = CNODE;
    cvt_bf<<<(cn * 256 + 255) / 256, 256, 0, stream>>>(aggS + (size_t)n0 * 256, Sbf, cn * 256);
    dim3 g6((cn + 127) / 128, 2);
    gemm128<2, 0><<<g6, 256, 0, stream>>>(Sbf, Wf2T, nullptr, outp + (size_t)n0 * 256,
                                          cn, 256, 256, nullptr, 0,
                                          nullptr, nullptr, nullptr, nullptr, nullptr, cntf + n0, b_f2, 0.1f);
  }
}

// Round 5
// 3447.059 us; speedup vs baseline: 2.8443x; 1.4888x over previous
//
#include <hip/hip_runtime.h>

// EGNN layer: N=50000 nodes, E=800000 edges, H=256.
// Round 5: dispatch-count collapse. GEMM2 epilogue emits att-dot partials
// (aw4), GEMM3 is dot-only (cw4) -> edge_dots + c1 buffer deleted.
// node GEMM gathers [hbf|aggbf] rows (build_nodein deleted). edge_fb uses
// precomputed CSR-ordered dn and writes Sbf bf16 directly.

#define NN 50000
#define EE 800000

typedef unsigned short u16;
typedef float f32x4 __attribute__((ext_vector_type(4)));
typedef short bf16x8 __attribute__((ext_vector_type(8)));

__device__ __forceinline__ u16 f2bf(float f) {
  unsigned u = __float_as_uint(f);
  u = (u + 0x7FFFu + ((u >> 16) & 1u)) >> 16;
  return (u16)u;
}
__device__ __forceinline__ float bf2f(u16 s) {
  return __uint_as_float(((unsigned)s) << 16);
}
__device__ __forceinline__ float silu_f(float x) { return x / (1.f + __expf(-x)); }

__device__ __forceinline__ void gload16(const void* g, void* l) {
  __builtin_amdgcn_global_load_lds(
      (const __attribute__((address_space(1))) void*)g,
      (__attribute__((address_space(3))) void*)l, 16, 0, 0);
}

// ---------------- 128x128 MFMA GEMM ------------------------------------------
// MODE 0: silu -> bf16
// MODE 1: none -> f32
// MODE 2: f32 out += scale*(acc + cnt[m]*b2[n])
// MODE 3: silu -> bf16 + per-row dot partials dp4 (dot with wvec)
// MODE 4: dot-only: dp4 partials of silu(acc+bias)*wvec (no main output)
// GATHER 0: A normal; 1: edge rows [hbf[row]|hbf[col]|tail]; 2: node rows [hbf|src2]
template <int MODE, int GATHER>
__global__ __launch_bounds__(256) void gemm128(
    const u16* __restrict__ A, const u16* __restrict__ BT,
    const float* __restrict__ bias, void* __restrict__ outp,
    int Mh, int Nc, int K, const int* __restrict__ meta, int cidx,
    const u16* __restrict__ hbf, const int* __restrict__ rowp,
    const int* __restrict__ colp, const int* __restrict__ perm,
    const u16* __restrict__ tail, const u16* __restrict__ src2,
    const float* __restrict__ wvec, float* __restrict__ dp4,
    const float* __restrict__ cnt, const float* __restrict__ b2, float scale) {
  const int M = meta ? meta[2 * cidx + 1] : Mh;
  const int m0 = blockIdx.x * 128, n0 = blockIdx.y * 128;
  if (m0 >= M) return;
  __shared__ __align__(16) u16 As[128][32];
  __shared__ __align__(16) u16 Bs[128][32];
  const int tid = threadIdx.x, w = tid >> 6, lane = tid & 63;
  const int srow = lane >> 2, sch = (lane & 3) * 8;
  const int r0 = w * 32 + srow, r1 = r0 + 16;

  u16* as0 = &As[w * 32][0];
  u16* as1 = &As[w * 32 + 16][0];
  u16* bs0 = &Bs[w * 32][0];
  u16* bs1 = &Bs[w * 32 + 16][0];

  const u16 *a0r, *a0c, *a0t, *a1r, *a1c, *a1t;
  a0c = a0t = a1c = a1t = nullptr;
  if (GATHER == 1) {
    const int eb = meta[2 * cidx];
    int le0 = m0 + r0; if (le0 > M - 1) le0 = M - 1;
    int le1 = m0 + r1; if (le1 > M - 1) le1 = M - 1;
    const int e0 = perm[eb + le0], e1 = perm[eb + le1];
    a0r = hbf + (size_t)rowp[e0] * 256; a0c = hbf + (size_t)colp[e0] * 256;
    a1r = hbf + (size_t)rowp[e1] * 256; a1c = hbf + (size_t)colp[e1] * 256;
    a0t = tail + (size_t)le0 * 32;      a1t = tail + (size_t)le1 * 32;
  } else if (GATHER == 2) {
    int q0 = m0 + r0; if (q0 > M - 1) q0 = M - 1;
    int q1 = m0 + r1; if (q1 > M - 1) q1 = M - 1;
    a0r = hbf + (size_t)q0 * 256;  a0c = src2 + (size_t)q0 * 256;
    a1r = hbf + (size_t)q1 * 256;  a1c = src2 + (size_t)q1 * 256;
  } else {
    a0r = A + (size_t)(m0 + r0) * K;
    a1r = A + (size_t)(m0 + r1) * K;
  }
  const u16* b0 = BT + (size_t)(n0 + r0) * K;
  const u16* b1 = BT + (size_t)(n0 + r1) * K;

  f32x4 acc[4][4] = {};
  const int l15 = lane & 15, ko = (lane >> 4) * 8;
  const int ar0 = (w >> 1) * 64, br0 = (w & 1) * 64;

  for (int k0 = 0; k0 < K; k0 += 32) {
    const u16 *pa0, *pa1;
    if (GATHER == 1) {
      if (k0 < 256)      { pa0 = a0r + k0;         pa1 = a1r + k0; }
      else if (k0 < 512) { pa0 = a0c + (k0 - 256); pa1 = a1c + (k0 - 256); }
      else               { pa0 = a0t;              pa1 = a1t; }
    } else if (GATHER == 2) {
      if (k0 < 256)      { pa0 = a0r + k0;         pa1 = a1r + k0; }
      else               { pa0 = a0c + (k0 - 256); pa1 = a1c + (k0 - 256); }
    } else { pa0 = a0r + k0; pa1 = a1r + k0; }
    gload16(pa0 + sch, as0);
    gload16(pa1 + sch, as1);
    gload16(b0 + k0 + sch, bs0);
    gload16(b1 + k0 + sch, bs1);
    __syncthreads();
    bf16x8 af[4], bfr[4];
#pragma unroll
    for (int i = 0; i < 4; i++)
      af[i] = *reinterpret_cast<const bf16x8*>(&As[ar0 + i * 16 + l15][ko]);
#pragma unroll
    for (int j = 0; j < 4; j++)
      bfr[j] = *reinterpret_cast<const bf16x8*>(&Bs[br0 + j * 16 + l15][ko]);
#pragma unroll
    for (int i = 0; i < 4; i++)
#pragma unroll
      for (int j = 0; j < 4; j++)
        acc[i][j] = __builtin_amdgcn_mfma_f32_16x16x32_bf16(af[i], bfr[j], acc[i][j], 0, 0, 0);
    __syncthreads();
  }

  const int rb = m0 + ar0 + ((lane >> 4) << 2);
  float ds[4][4];
  if (MODE == 3 || MODE == 4) {
#pragma unroll
    for (int i = 0; i < 4; i++)
#pragma unroll
      for (int t = 0; t < 4; t++) ds[i][t] = 0.f;
  }
#pragma unroll
  for (int j = 0; j < 4; j++) {
    const int gc = n0 + br0 + j * 16 + l15;
    const float bz = (MODE == 2) ? 0.f : bias[gc];
    const float wv = (MODE == 3 || MODE == 4) ? wvec[gc] : 0.f;
#pragma unroll
    for (int i = 0; i < 4; i++) {
#pragma unroll
      for (int t = 0; t < 4; t++) {
        const int gr = rb + i * 16 + t;
        float v = acc[i][j][t] + bz;
        if (MODE == 0) {
          if (gr < M) ((u16*)outp)[(size_t)gr * Nc + gc] = f2bf(silu_f(v));
        } else if (MODE == 1) {
          if (gr < M) ((float*)outp)[(size_t)gr * Nc + gc] = v;
        } else if (MODE == 2) {
          if (gr < M) ((float*)outp)[(size_t)gr * Nc + gc] += scale * (v + cnt[gr] * b2[gc]);
        } else if (MODE == 3) {
          float sv = silu_f(v);
          if (gr < M) ((u16*)outp)[(size_t)gr * Nc + gc] = f2bf(sv);
          ds[i][t] += sv * wv;
        } else if (MODE == 4) {
          ds[i][t] += silu_f(v) * wv;
        }
      }
    }
  }
  if (MODE == 3 || MODE == 4) {
    const int idx = blockIdx.y * 2 + (w & 1);
#pragma unroll
    for (int i = 0; i < 4; i++) {
#pragma unroll
      for (int t = 0; t < 4; t++) {
        float s = ds[i][t];
        s += __shfl_xor(s, 1); s += __shfl_xor(s, 2);
        s += __shfl_xor(s, 4); s += __shfl_xor(s, 8);
        const int gr = rb + i * 16 + t;
        if (l15 == 0 && gr < M) dp4[(size_t)gr * 4 + idx] = s;
      }
    }
  }
}

// ---------------- weight transpose + bf16: src[K,N] -> dst[N,Kpad] -----------
__global__ void wtrans(const float* __restrict__ src, u16* __restrict__ dst,
                       int K, int Nn, int Kpad) {
  int t = blockIdx.x * 256 + threadIdx.x;
  if (t >= Nn * Kpad) return;
  int n = t / Kpad, k = t - n * Kpad;
  float v = (k < K) ? src[(size_t)k * Nn + n] : 0.f;
  dst[t] = f2bf(v);
}

__global__ void edge_geom(const float* __restrict__ pos, const int* __restrict__ row,
                          const int* __restrict__ colx, float* __restrict__ dist,
                          int* __restrict__ icnt) {
  int e = blockIdx.x * 256 + threadIdx.x;
  if (e >= EE) return;
  int r = row[e], c = colx[e];
  float d0 = pos[r * 3 + 0] - pos[c * 3 + 0];
  float d1 = pos[r * 3 + 1] - pos[c * 3 + 1];
  float d2 = pos[r * 3 + 2] - pos[c * 3 + 2];
  dist[e] = fmaxf(sqrtf(d0 * d0 + d1 * d1 + d2 * d2), 1e-5f);
  atomicAdd(&icnt[r], 1);
}

__global__ __launch_bounds__(1024) void scan_ptr(const int* __restrict__ icnt,
                                                 int* __restrict__ ptr) {
  __shared__ int ls[1024];
  const int t = threadIdx.x;
  const int SEG = (NN + 1023) / 1024;
  int s0 = t * SEG;
  int s1 = s0 + SEG; if (s1 > NN) s1 = NN;
  int sum = 0;
  for (int i = s0; i < s1; i++) sum += icnt[i];
  ls[t] = sum;
  __syncthreads();
  for (int off = 1; off < 1024; off <<= 1) {
    int v = (t >= off) ? ls[t - off] : 0;
    __syncthreads();
    ls[t] += v;
    __syncthreads();
  }
  int run = ls[t] - sum;
  for (int i = s0; i < s1; i++) { ptr[i] = run; run += icnt[i]; }
  if (t == 1023) ptr[NN] = ls[1023];
}

__global__ void copy_head(const int* __restrict__ ptr, int* __restrict__ head,
                          float* __restrict__ cntf) {
  int n = blockIdx.x * 256 + threadIdx.x;
  if (n >= NN) return;
  head[n] = ptr[n];
  cntf[n] = (float)(ptr[n + 1] - ptr[n]);
}

__global__ void fill_perm(const int* __restrict__ row, int* __restrict__ head,
                          int* __restrict__ perm) {
  int e = blockIdx.x * 256 + threadIdx.x;
  if (e >= EE) return;
  int p = atomicAdd(&head[row[e]], 1);
  perm[p] = e;
}

__global__ void chunk_meta(const int* __restrict__ ptr, int* __restrict__ meta,
                           int CN, int nch, int capE) {
  int c = blockIdx.x * 256 + threadIdx.x;
  if (c >= nch) return;
  int lo = c * CN;
  int hi = lo + CN; if (hi > NN) hi = NN;
  int b = ptr[lo];
  int cc = ptr[hi] - b;
  if (cc > capE) cc = capE;
  meta[2 * c + 0] = b;
  meta[2 * c + 1] = cc;
}

__global__ void build_tail(const float* __restrict__ dist, const float* __restrict__ eattr,
                           const int* __restrict__ perm, const int* __restrict__ meta,
                           int cidx, u16* __restrict__ tail, int capE) {
  int t = blockIdx.x * 256 + threadIdx.x;
  if (t >= capE * 32) return;
  int le = t >> 5, j = t & 31;
  if (le >= meta[2 * cidx + 1]) return;
  int e = perm[meta[2 * cidx] + le];
  float v = 0.f;
  if (j == 0) v = dist[e];
  else if (j < 14) v = eattr[(size_t)e * 13 + (j - 1)];
  tail[t] = f2bf(v);
}

__global__ __launch_bounds__(128) void ln_512(u16* __restrict__ t,
                                              const float* __restrict__ g,
                                              const float* __restrict__ b,
                                              int Mh, const int* __restrict__ meta, int cidx) {
  int row = blockIdx.x;
  if (row >= (meta ? meta[2 * cidx + 1] : Mh)) return;
  int tid = threadIdx.x;
  size_t base = (size_t)row * 512 + tid * 4;
  ushort4 xv = *reinterpret_cast<const ushort4*>(&t[base]);
  float x0 = bf2f(xv.x), x1 = bf2f(xv.y), x2 = bf2f(xv.z), x3 = bf2f(xv.w);
  float s1 = x0 + x1 + x2 + x3;
  float s2 = x0 * x0 + x1 * x1 + x2 * x2 + x3 * x3;
  for (int o = 32; o; o >>= 1) { s1 += __shfl_xor(s1, o); s2 += __shfl_xor(s2, o); }
  __shared__ float red[4];
  if ((tid & 63) == 0) { red[tid >> 6] = s1; red[2 + (tid >> 6)] = s2; }
  __syncthreads();
  s1 = red[0] + red[1]; s2 = red[2] + red[3];
  float mu = s1 * (1.f / 512.f);
  float var = s2 * (1.f / 512.f) - mu * mu;
  float inv = rsqrtf(var + 1e-5f);
  int c = tid * 4;
  ushort4 yv;
  yv.x = f2bf((x0 - mu) * inv * g[c + 0] + b[c + 0]);
  yv.y = f2bf((x1 - mu) * inv * g[c + 1] + b[c + 1]);
  yv.z = f2bf((x2 - mu) * inv * g[c + 2] + b[c + 2]);
  yv.w = f2bf((x3 - mu) * inv * g[c + 3] + b[c + 3]);
  *reinterpret_cast<ushort4*>(&t[base]) = yv;
}

// ---------------- per-node aggregation; att/cw from GEMM partials ------------
__global__ __launch_bounds__(256) void node_agg(
    const u16* __restrict__ m, const float* __restrict__ aw4,
    const float* __restrict__ cw4, const float* __restrict__ ba,
    const float* __restrict__ pos, const int* __restrict__ colx,
    const int* __restrict__ perm, const int* __restrict__ ptr,
    const int* __restrict__ meta, int cidx,
    u16* __restrict__ aggbf, float* __restrict__ cagg, int nlo, int cn) {
  int w = threadIdx.x >> 6, lane = threadIdx.x & 63;
  int nl = blockIdx.x * 4 + w;
  if (nl >= cn) return;
  int n = nlo + nl;
  int base = meta[2 * cidx];
  int p0 = ptr[n], p1 = ptr[n + 1];
  float ba0 = ba[0];
  float a0 = 0.f, a1 = 0.f, a2 = 0.f, a3 = 0.f;
  for (int p = p0; p < p1; p++) {
    int le = p - base;
    float aw = aw4[(size_t)le * 4 + 0] + aw4[(size_t)le * 4 + 1] +
               aw4[(size_t)le * 4 + 2] + aw4[(size_t)le * 4 + 3];
    float at = 1.f / (1.f + __expf(-(aw + ba0)));
    ushort4 mv = *reinterpret_cast<const ushort4*>(&m[(size_t)le * 256 + lane * 4]);
    a0 += at * bf2f(mv.x); a1 += at * bf2f(mv.y);
    a2 += at * bf2f(mv.z); a3 += at * bf2f(mv.w);
  }
  ushort4 ov;
  ov.x = f2bf(a0); ov.y = f2bf(a1); ov.z = f2bf(a2); ov.w = f2bf(a3);
  *reinterpret_cast<ushort4*>(&aggbf[(size_t)n * 256 + lane * 4]) = ov;
  if (lane < 3) {
    float pr = pos[n * 3 + lane], s = 0.f;
    for (int p = p0; p < p1; p++) {
      int le = p - base;
      float cw = cw4[(size_t)le * 4 + 0] + cw4[(size_t)le * 4 + 1] +
                 cw4[(size_t)le * 4 + 2] + cw4[(size_t)le * 4 + 3];
      int c = colx[perm[p]];
      s += cw * (pr - pos[c * 3 + lane]);
    }
    cagg[n * 3 + lane] = s;
  }
}

__global__ __launch_bounds__(64) void hmid_ln(const float* __restrict__ h,
                                              const float* __restrict__ hupd,
                                              const float* __restrict__ g,
                                              const float* __restrict__ b,
                                              float* __restrict__ outp) {
  int row = blockIdx.x, lane = threadIdx.x;
  size_t base = (size_t)row * 256 + lane * 4;
  float x[4];
#pragma unroll
  for (int i = 0; i < 4; i++) x[i] = h[base + i] + hupd[base + i];
  float s1 = x[0] + x[1] + x[2] + x[3];
  float s2 = x[0] * x[0] + x[1] * x[1] + x[2] * x[2] + x[3] * x[3];
  for (int o = 32; o; o >>= 1) { s1 += __shfl_xor(s1, o); s2 += __shfl_xor(s2, o); }
  float mu = s1 * (1.f / 256.f);
  float var = s2 * (1.f / 256.f) - mu * mu;
  float inv = rsqrtf(var + 1e-5f);
#pragma unroll
  for (int i = 0; i < 4; i++)
    outp[base + i] = (x[i] - mu) * inv * g[lane * 4 + i] + b[lane * 4 + i];
}

__global__ void posnew_k(const float* __restrict__ pos, const float* __restrict__ cagg,
                         float* __restrict__ op) {
  int t = blockIdx.x * 256 + threadIdx.x;
  if (t >= NN * 3) return;
  op[t] = pos[t] + cagg[t];
}

// ---------------- dn_new in CSR order (coalesced writes) ---------------------
__global__ void dnn_k(const float* __restrict__ posn, const int* __restrict__ rowp,
                      const int* __restrict__ colp, const int* __restrict__ perm,
                      float* __restrict__ dnc) {
  int p = blockIdx.x * 256 + threadIdx.x;
  if (p >= EE) return;
  int e = perm[p];
  int r = rowp[e], c = colp[e];
  float d0 = posn[r * 3 + 0] - posn[c * 3 + 0];
  float d1 = posn[r * 3 + 1] - posn[c * 3 + 1];
  float d2 = posn[r * 3 + 2] - posn[c * 3 + 2];
  dnc[p] = fmaxf(sqrtf(d0 * d0 + d1 * d1 + d2 * d2), 1e-5f);
}

// ---------------- feedback: Sbf[n] = bf16( sum_p silu(dn*Wf1+bf1) ) ----------
__global__ __launch_bounds__(256) void edge_fb2(
    const float* __restrict__ dnc, const int* __restrict__ ptr,
    const float* __restrict__ Wf1, const float* __restrict__ bf1,
    u16* __restrict__ Sbf) {
  int w = threadIdx.x >> 6, lane = threadIdx.x & 63;
  int n = blockIdx.x * 4 + w;
  if (n >= NN) return;
  float w0 = Wf1[lane * 4 + 0], w1 = Wf1[lane * 4 + 1];
  float w2 = Wf1[lane * 4 + 2], w3 = Wf1[lane * 4 + 3];
  float b0 = bf1[lane * 4 + 0], b1 = bf1[lane * 4 + 1];
  float b2 = bf1[lane * 4 + 2], b3 = bf1[lane * 4 + 3];
  float a0 = 0.f, a1 = 0.f, a2 = 0.f, a3 = 0.f;
  int p0 = ptr[n], p1 = ptr[n + 1];
  for (int p = p0; p < p1; p++) {
    float dn = dnc[p];
    a0 += silu_f(dn * w0 + b0);
    a1 += silu_f(dn * w1 + b1);
    a2 += silu_f(dn * w2 + b2);
    a3 += silu_f(dn * w3 + b3);
  }
  ushort4 ov;
  ov.x = f2bf(a0); ov.y = f2bf(a1); ov.z = f2bf(a2); ov.w = f2bf(a3);
  *reinterpret_cast<ushort4*>(&Sbf[(size_t)n * 256 + lane * 4]) = ov;
}

__global__ void cvt_bf(const float* __restrict__ src, u16* __restrict__ dst, int n) {
  int t = blockIdx.x * 256 + threadIdx.x;
  if (t < n) dst[t] = f2bf(src[t]);
}

extern "C" void kernel_launch(void* const* d_in, const int* in_sizes, int n_in,
                              void* d_out, int out_size, void* d_ws, size_t ws_size,
                              hipStream_t stream) {
  const float* h     = (const float*)d_in[0];
  const float* pos   = (const float*)d_in[1];
  const int*   eidx  = (const int*)d_in[2];
  const float* eattr = (const float*)d_in[3];
  const float* W_e1 = (const float*)d_in[4];  const float* b_e1 = (const float*)d_in[5];
  const float* g_e  = (const float*)d_in[6];  const float* be_ln = (const float*)d_in[7];
  const float* W_e2 = (const float*)d_in[8];  const float* b_e2 = (const float*)d_in[9];
  const float* W_n1 = (const float*)d_in[10]; const float* b_n1 = (const float*)d_in[11];
  const float* g_n  = (const float*)d_in[12]; const float* bn_ln = (const float*)d_in[13];
  const float* W_n2 = (const float*)d_in[14]; const float* b_n2 = (const float*)d_in[15];
  const float* g_o  = (const float*)d_in[16]; const float* bo_ln = (const float*)d_in[17];
  const float* W_c1 = (const float*)d_in[18]; const float* b_c1 = (const float*)d_in[19];
  const float* W_c2 = (const float*)d_in[20];
  const float* W_a  = (const float*)d_in[21]; const float* b_a = (const float*)d_in[22];
  const float* W_f1 = (const float*)d_in[23]; const float* b_f1 = (const float*)d_in[24];
  const float* W_f2 = (const float*)d_in[25]; const float* b_f2 = (const float*)d_in[26];

  float* outp = (float*)d_out;
  float* out_pos = outp + (size_t)NN * 256;

  char* base = (char*)d_ws;
  size_t off = 0;
  auto alloc = [&](size_t bytes) -> void* {
    off = (off + 255) & ~(size_t)255;
    void* p = base + off;
    off += bytes;
    return p;
  };
  // ---- persistent (~87 MB) ----
  u16* We1T = (u16*)alloc((size_t)512 * 544 * 2);
  u16* We2T = (u16*)alloc((size_t)256 * 512 * 2);
  u16* Wn1T = (u16*)alloc((size_t)512 * 512 * 2);
  u16* Wn2T = (u16*)alloc((size_t)256 * 512 * 2);
  u16* Wc1T = (u16*)alloc((size_t)256 * 256 * 2);
  u16* Wf2T = (u16*)alloc((size_t)256 * 256 * 2);
  u16* hbf  = (u16*)alloc((size_t)NN * 256 * 2);
  float* dist = (float*)alloc((size_t)EE * 4);      // reused as dnc in phase C
  int*   icnt = (int*)alloc((size_t)NN * 4);
  int*   ptr  = (int*)alloc((size_t)(NN + 1) * 4);
  int*   head = (int*)alloc((size_t)NN * 4);
  int*   perm = (int*)alloc((size_t)EE * 4);
  float* cntf = (float*)alloc((size_t)NN * 4);
  float* cagg = (float*)alloc((size_t)NN * 12);
  int*   meta = (int*)alloc((size_t)8192);
  u16*   aggbf = (u16*)alloc((size_t)NN * 256 * 2);
  u16*   Sbf   = (u16*)alloc((size_t)50048 * 256 * 2);

  // ---- arena: 1632 B/edge ----
  off = (off + 255) & ~(size_t)255;
  char* arena = base + off;
  size_t avail = (ws_size > off) ? ws_size - off : 0;
  int CN = 4096;
  while (CN > 64 && (size_t)(CN * 16 + 4096) * 1632 > avail) CN >>= 1;
  const int capE = CN * 16 + 4096;                      // multiple of 128
  u16*   t1   = (u16*)arena;                            // [capE][512]
  u16*   mBuf = (u16*)(arena + (size_t)capE * 1024);    // [capE][256]
  u16*   tail = (u16*)(arena + (size_t)capE * 1536);    // [capE][32]
  float* aw4  = (float*)(arena + (size_t)capE * 1600);  // [capE][4]
  float* cw4  = (float*)(arena + (size_t)capE * 1616);  // [capE][4]
  long cnl = (long)(avail / 2048) & ~127L;              // node overlay: t2+hupd
  if (cnl > 50048) cnl = 50048;
  if (cnl < 128) cnl = 128;
  const int CNODE = (int)cnl;
  u16*   t2   = (u16*)arena;                            // [CNODE][512]
  float* hupd = (float*)(arena + (size_t)CNODE * 1024); // [CNODE][256]

  const int* rowp = eidx;
  const int* colp = eidx + EE;
  const int nch = (NN + CN - 1) / CN;

  hipMemsetAsync(icnt, 0, (size_t)NN * 4, stream);

  wtrans<<<(512 * 544 + 255) / 256, 256, 0, stream>>>(W_e1, We1T, 526, 512, 544);
  wtrans<<<(256 * 512 + 255) / 256, 256, 0, stream>>>(W_e2, We2T, 512, 256, 512);
  wtrans<<<(512 * 512 + 255) / 256, 256, 0, stream>>>(W_n1, Wn1T, 512, 512, 512);
  wtrans<<<(256 * 512 + 255) / 256, 256, 0, stream>>>(W_n2, Wn2T, 512, 256, 512);
  wtrans<<<(256 * 256 + 255) / 256, 256, 0, stream>>>(W_c1, Wc1T, 256, 256, 256);
  wtrans<<<(256 * 256 + 255) / 256, 256, 0, stream>>>(W_f2, Wf2T, 256, 256, 256);
  cvt_bf<<<(NN * 256 + 255) / 256, 256, 0, stream>>>(h, hbf, NN * 256);

  // ---- CSR build ----
  edge_geom<<<(EE + 255) / 256, 256, 0, stream>>>(pos, rowp, colp, dist, icnt);
  scan_ptr<<<1, 1024, 0, stream>>>(icnt, ptr);
  copy_head<<<(NN + 255) / 256, 256, 0, stream>>>(ptr, head, cntf);
  fill_perm<<<(EE + 255) / 256, 256, 0, stream>>>(rowp, head, perm);
  chunk_meta<<<(nch + 255) / 256, 256, 0, stream>>>(ptr, meta, CN, nch, capE);

  // ---- phase A: edge pipeline ----
  for (int c = 0; c < nch; c++) {
    int nlo = c * CN;
    int cn = NN - nlo; if (cn > CN) cn = CN;
    build_tail<<<(capE * 32 + 255) / 256, 256, 0, stream>>>(dist, eattr, perm, meta, c, tail, capE);
    dim3 g1(capE / 128, 4);
    gemm128<0, 1><<<g1, 256, 0, stream>>>(nullptr, We1T, b_e1, t1, 0, 512, 544, meta, c,
                                          hbf, rowp, colp, perm, tail, nullptr,
                                          nullptr, nullptr, nullptr, nullptr, 0.f);
    ln_512<<<capE, 128, 0, stream>>>(t1, g_e, be_ln, 0, meta, c);
    dim3 g2(capE / 128, 2);
    gemm128<3, 0><<<g2, 256, 0, stream>>>(t1, We2T, b_e2, mBuf, 0, 256, 512, meta, c,
                                          nullptr, nullptr, nullptr, nullptr, nullptr, nullptr,
                                          W_a, aw4, nullptr, nullptr, 0.f);
    gemm128<4, 0><<<g2, 256, 0, stream>>>(mBuf, Wc1T, b_c1, nullptr, 0, 256, 256, meta, c,
                                          nullptr, nullptr, nullptr, nullptr, nullptr, nullptr,
                                          W_c2, cw4, nullptr, nullptr, 0.f);
    node_agg<<<(cn + 3) / 4, 256, 0, stream>>>(mBuf, aw4, cw4, b_a, pos, colp, perm, ptr,
                                               meta, c, aggbf, cagg, nlo, cn);
  }

  // ---- phase B: node pipeline (gather [hbf|aggbf]) ----
  for (int n0 = 0; n0 < NN; n0 += CNODE) {
    int cn = NN - n0; if (cn > CNODE) cn = CNODE;
    dim3 g4((cn + 127) / 128, 4);
    gemm128<0, 2><<<g4, 256, 0, stream>>>(nullptr, Wn1T, b_n1, t2, cn, 512, 512, nullptr, 0,
                                          hbf + (size_t)n0 * 256, nullptr, nullptr, nullptr,
                                          nullptr, aggbf + (size_t)n0 * 256,
                                          nullptr, nullptr, nullptr, nullptr, 0.f);
    ln_512<<<cn, 128, 0, stream>>>(t2, g_n, bn_ln, cn, nullptr, 0);
    dim3 g5((cn + 127) / 128, 2);
    gemm128<1, 0><<<g5, 256, 0, stream>>>(t2, Wn2T, b_n2, hupd, cn, 256, 512, nullptr, 0,
                                          nullptr, nullptr, nullptr, nullptr, nullptr, nullptr,
                                          nullptr, nullptr, nullptr, nullptr, 0.f);
    hmid_ln<<<cn, 64, 0, stream>>>(h + (size_t)n0 * 256, hupd, g_o, bo_ln, outp + (size_t)n0 * 256);
  }

  // ---- phase C: coords + feedback ----
  posnew_k<<<(NN * 3 + 255) / 256, 256, 0, stream>>>(pos, cagg, out_pos);
  dnn_k<<<(EE + 255) / 256, 256, 0, stream>>>(out_pos, rowp, colp, perm, dist);
  edge_fb2<<<(NN + 3) / 4, 256, 0, stream>>>(dist, ptr, W_f1, b_f1, Sbf);
  dim3 g6((NN + 127) / 128, 2);
  gemm128<2, 0><<<g6, 256, 0, stream>>>(Sbf, Wf2T, nullptr, outp, NN, 256, 256, nullptr, 0,
                                        nullptr, nullptr, nullptr, nullptr, nullptr, nullptr,
                                        nullptr, nullptr, cntf, b_f2, 0.1f);
}